// Round 6
// baseline (389.458 us; speedup 1.0000x reference)
//
#include <hip/hip_runtime.h>

#define NN 100000      // nodes
#define NE 1600000     // edges
#define DD 128         // input dim (elements per row)
#define MD 512         // mlp dim = 128*4
#define SEL 16384      // senders count
#define MROWS 32768    // senders + receivers rows
#define NBKT 196       // buckets of 512 nodes
#define TILE 4096      // edges per k_binA block
#define SEGCAP 16384   // padded CSR slots per bucket (mean ~9984, hard cap)

typedef __attribute__((ext_vector_type(8))) short bf16x8;
typedef __attribute__((ext_vector_type(4))) float f32x4;

__device__ __forceinline__ unsigned short f2bf(float f) {
  unsigned u = __float_as_uint(f);
  u += 0x7fff + ((u >> 16) & 1);   // round-to-nearest-even
  return (unsigned short)(u >> 16);
}
__device__ __forceinline__ float bflo(unsigned v) { return __uint_as_float(v << 16); }
__device__ __forceinline__ float bfhi(unsigned v) { return __uint_as_float(v & 0xffff0000u); }

// ---- bucket histogram over dst (one streaming pass) ----
__global__ __launch_bounds__(256) void k_histo(const int* __restrict__ dst,
                                               int* __restrict__ bcnt) {
  __shared__ int h[NBKT];
  for (int i = threadIdx.x; i < NBKT; i += 256) h[i] = 0;
  __syncthreads();
  for (long e = blockIdx.x * 256L + threadIdx.x; e < NE; e += (long)gridDim.x * 256)
    atomicAdd(&h[dst[e] >> 9], 1);
  __syncthreads();
  for (int i = threadIdx.x; i < NBKT; i += 256)
    if (h[i]) atomicAdd(&bcnt[i], h[i]);
}

// ---- scan bucket counts -> bstart (ebuf layout) + live cursor ----
__global__ __launch_bounds__(256) void k_bscan(const int* __restrict__ bcnt,
                                               int* __restrict__ gcursor,
                                               int* __restrict__ bstart) {
  __shared__ int sm[256];
  int tid = threadIdx.x;
  int v = (tid < NBKT) ? bcnt[tid] : 0;
  sm[tid] = v;
  __syncthreads();
  for (int o = 1; o < 256; o <<= 1) {
    int t = (tid >= o) ? sm[tid - o] : 0;
    __syncthreads();
    sm[tid] += t;
    __syncthreads();
  }
  if (tid < NBKT) {
    int ex = sm[tid] - v;
    gcursor[tid] = ex;
    bstart[tid] = ex;
  }
}

// ---- bin edges by bucket: ebuf[slot] = src<<9 | (dst&511), bucket-contig ----
__global__ __launch_bounds__(256) void k_binA(const int* __restrict__ src,
                                              const int* __restrict__ dst,
                                              int* __restrict__ gcursor,
                                              unsigned* __restrict__ ebuf) {
  __shared__ int hist[NBKT];
  __shared__ int base[NBKT];
  __shared__ int cnt2[NBKT];
  const int tid = threadIdx.x;
  const long e0 = (long)blockIdx.x * TILE;
  for (int i = tid; i < NBKT; i += 256) { hist[i] = 0; cnt2[i] = 0; }
  __syncthreads();
  unsigned pk[16]; int bk[16];
  #pragma unroll
  for (int k = 0; k < 16; ++k) {
    const long e = e0 + k * 256 + tid;
    bk[k] = -1;
    if (e < NE) {
      const int d = dst[e], s = src[e];
      bk[k] = d >> 9;
      pk[k] = ((unsigned)s << 9) | (unsigned)(d & 511);
      atomicAdd(&hist[bk[k]], 1);
    }
  }
  __syncthreads();
  for (int i = tid; i < NBKT; i += 256)
    base[i] = atomicAdd(&gcursor[i], hist[i]);
  __syncthreads();
  #pragma unroll
  for (int k = 0; k < 16; ++k) {
    if (bk[k] >= 0) {
      const int lp = atomicAdd(&cnt2[bk[k]], 1);
      ebuf[base[bk[k]] + lp] = pk[k];
    }
  }
}

// ---- per-bucket degree + dinv + local padded-offset scan + bucket totals ----
__global__ __launch_bounds__(256) void k_degB(const unsigned* __restrict__ ebuf,
                                              const int* __restrict__ bstart,
                                              const int* __restrict__ bcnt,
                                              int* __restrict__ deg,
                                              float* __restrict__ dinv,
                                              int* __restrict__ excl,
                                              int* __restrict__ btot,
                                              unsigned short* __restrict__ x0,
                                              unsigned short* __restrict__ x1,
                                              unsigned short* __restrict__ x2) {
  __shared__ int ld[512];
  __shared__ int ps[256];
  const int b = blockIdx.x;
  const int n0 = b << 9;
  const int nn = min(512, NN - n0);
  const int tid = threadIdx.x;
  for (int i = tid; i < 512; i += 256) ld[i] = 0;
  __syncthreads();
  const int s0 = bstart[b], c = bcnt[b];
  for (int i = tid; i < c; i += 256) atomicAdd(&ld[ebuf[s0 + i] & 511], 1);
  __syncthreads();
  const int d0 = (tid * 2 < nn) ? ld[tid * 2] : 0;
  const int d1 = (tid * 2 + 1 < nn) ? ld[tid * 2 + 1] : 0;
  const int p0 = (d0 + 7) & ~7, p1 = (d1 + 7) & ~7;
  ps[tid] = p0 + p1;
  __syncthreads();
  for (int o = 1; o < 256; o <<= 1) {
    int t2 = (tid >= o) ? ps[tid - o] : 0;
    __syncthreads();
    ps[tid] += t2;
    __syncthreads();
  }
  const int exbase = ps[tid] - (p0 + p1);
  if (tid * 2 < nn) {
    deg[n0 + tid * 2] = d0;
    dinv[n0 + tid * 2] = rsqrtf(fmaxf((float)d0, 1.f));
    excl[n0 + tid * 2] = exbase;
  }
  if (tid * 2 + 1 < nn) {
    deg[n0 + tid * 2 + 1] = d1;
    dinv[n0 + tid * 2 + 1] = rsqrtf(fmaxf((float)d1, 1.f));
    excl[n0 + tid * 2 + 1] = exbase + p0;
  }
  if (tid == 255) btot[b] = ps[255];
  if (b == 0 && tid < 64) {  // zero the sentinel row NN of each x buffer
    ((unsigned*)(x0 + (size_t)NN * DD))[tid] = 0u;
    ((unsigned*)(x1 + (size_t)NN * DD))[tid] = 0u;
    ((unsigned*)(x2 + (size_t)NN * DD))[tid] = 0u;
  }
}

// ---- scan bucket padded totals -> bbase (csr layout) ----
__global__ __launch_bounds__(256) void k_bscan2(const int* __restrict__ btot,
                                                int* __restrict__ bbase) {
  __shared__ int sm[256];
  int tid = threadIdx.x;
  int v = (tid < NBKT) ? btot[tid] : 0;
  sm[tid] = v;
  __syncthreads();
  for (int o = 1; o < 256; o <<= 1) {
    int t = (tid >= o) ? sm[tid - o] : 0;
    __syncthreads();
    sm[tid] += t;
    __syncthreads();
  }
  if (tid < NBKT) bbase[tid] = sm[tid] - v;
}

// ---- per-bucket LDS scatter into padded CSR, coalesced out; pads=NN ----
__global__ __launch_bounds__(256) void k_binB(const unsigned* __restrict__ ebuf,
                                              const int* __restrict__ bstart,
                                              const int* __restrict__ bcnt,
                                              const int* __restrict__ excl,
                                              const int* __restrict__ bbase,
                                              const int* __restrict__ btot,
                                              int* __restrict__ rowstart,
                                              int* __restrict__ csr) {
  __shared__ int seg[SEGCAP];
  __shared__ int rs[512];
  __shared__ int cnt[512];
  const int b = blockIdx.x;
  const int n0 = b << 9;
  const int nn = min(512, NN - n0);
  const int seg0 = bbase[b];
  const int seglen = btot[b];
  for (int i = threadIdx.x; i < nn; i += 256) {
    const int ex = excl[n0 + i];
    rs[i] = ex;
    cnt[i] = 0;
    rowstart[n0 + i] = seg0 + ex;
  }
  for (int i = threadIdx.x; i < seglen; i += 256) seg[i] = NN;  // sentinel pad
  __syncthreads();
  const int s0 = bstart[b], c = bcnt[b];
  for (int i = threadIdx.x; i < c; i += 256) {
    const unsigned e = ebuf[s0 + i];
    const int dl = e & 511;
    const int pos = rs[dl] + atomicAdd(&cnt[dl], 1);
    seg[pos] = (int)(e >> 9);
  }
  __syncthreads();
  for (int i = threadIdx.x; i < seglen; i += 256) csr[seg0 + i] = seg[i];
}

// ---- mark + compact the nodes needed by the final layer ----
__global__ void k_mark(const int* __restrict__ sl, const int* __restrict__ rl,
                       int* __restrict__ mark) {
  int i = blockIdx.x * blockDim.x + threadIdx.x;
  if (i < SEL) mark[sl[i]] = 1;
  else if (i < 2 * SEL) mark[rl[i - SEL]] = 1;
}

__global__ void k_compact(const int* __restrict__ mark, int* __restrict__ list,
                          int* __restrict__ cnt) {
  int n = blockIdx.x * blockDim.x + threadIdx.x;
  if (n < NN && mark[n]) {
    int p = atomicAdd(cnt, 1);
    list[p] = n;
  }
}

// ---- per-node aggregation of u = dinv*x: 8 unpredicated gathers in flight ----
// u_next[d] = dinv[d]^2 * sum_{s in N(d)} u[s]; pad slots hit zeroed row NN.
__device__ __forceinline__ void agg_row(int n, int lane,
                                        const int* __restrict__ rowstart,
                                        const int* __restrict__ deg,
                                        const int* __restrict__ csr,
                                        const float* __restrict__ dinv,
                                        const unsigned short* __restrict__ xin,
                                        unsigned short* __restrict__ xout) {
  const int start = rowstart[n];
  const int cntp = (deg[n] + 7) & ~7;
  float ax[8], ay[8];
  #pragma unroll
  for (int u = 0; u < 8; ++u) { ax[u] = 0.f; ay[u] = 0.f; }
  for (int j = 0; j < cntp; j += 8) {
    const int4 e0 = *(const int4*)(csr + start + j);
    const int4 e1 = *(const int4*)(csr + start + j + 4);
    unsigned v[8];
    v[0] = ((const unsigned*)(xin + (size_t)e0.x * DD))[lane];
    v[1] = ((const unsigned*)(xin + (size_t)e0.y * DD))[lane];
    v[2] = ((const unsigned*)(xin + (size_t)e0.z * DD))[lane];
    v[3] = ((const unsigned*)(xin + (size_t)e0.w * DD))[lane];
    v[4] = ((const unsigned*)(xin + (size_t)e1.x * DD))[lane];
    v[5] = ((const unsigned*)(xin + (size_t)e1.y * DD))[lane];
    v[6] = ((const unsigned*)(xin + (size_t)e1.z * DD))[lane];
    v[7] = ((const unsigned*)(xin + (size_t)e1.w * DD))[lane];
    #pragma unroll
    for (int u = 0; u < 8; ++u) { ax[u] += bflo(v[u]); ay[u] += bfhi(v[u]); }
  }
  const float s = dinv[n] * dinv[n];
  const float rx = (((ax[0] + ax[1]) + (ax[2] + ax[3])) + ((ax[4] + ax[5]) + (ax[6] + ax[7]))) * s;
  const float ry = (((ay[0] + ay[1]) + (ay[2] + ay[3])) + ((ay[4] + ay[5]) + (ay[6] + ay[7]))) * s;
  ((unsigned*)(xout + (size_t)n * DD))[lane] = ((unsigned)f2bf(ry) << 16) | (unsigned)f2bf(rx);
}

__global__ __launch_bounds__(256) void k_agg(const int* __restrict__ rowstart,
                                             const int* __restrict__ deg,
                                             const int* __restrict__ csr,
                                             const float* __restrict__ dinv,
                                             const unsigned short* __restrict__ xin,
                                             unsigned short* __restrict__ xout) {
  const int lane = threadIdx.x & 63;
  const int wid = (blockIdx.x * blockDim.x + threadIdx.x) >> 6;
  const int nw = (gridDim.x * blockDim.x) >> 6;
  for (int n = wid; n < NN; n += nw)
    agg_row(n, lane, rowstart, deg, csr, dinv, xin, xout);
}

__global__ __launch_bounds__(256) void k_agg_list(const int* __restrict__ rowstart,
                                                  const int* __restrict__ deg,
                                                  const int* __restrict__ csr,
                                                  const float* __restrict__ dinv,
                                                  const unsigned short* __restrict__ xin,
                                                  unsigned short* __restrict__ xout,
                                                  const int* __restrict__ list,
                                                  const int* __restrict__ lcnt) {
  const int lane = threadIdx.x & 63;
  const int wid = (blockIdx.x * blockDim.x + threadIdx.x) >> 6;
  const int nw = (gridDim.x * blockDim.x) >> 6;
  const int cl = *lcnt;
  for (int i = wid; i < cl; i += nw)
    agg_row(list[i], lane, rowstart, deg, csr, dinv, xin, xout);
}

// ---- gather + l2-normalize selected bf16 rows -> bf16 A-matrix slice ----
__global__ __launch_bounds__(256) void k_gnorm(const int* __restrict__ sl,
                                               const int* __restrict__ rl,
                                               const unsigned short* __restrict__ xin,
                                               unsigned short* __restrict__ Abf,
                                               int colbase) {
  const int lane = threadIdx.x & 63;
  const int row = blockIdx.x * 4 + (threadIdx.x >> 6);
  if (row >= MROWS) return;
  const int node = (row < SEL) ? sl[row] : rl[row - SEL];
  const unsigned v = ((const unsigned*)(xin + (size_t)node * DD))[lane];
  const float x0 = bflo(v), x1 = bfhi(v);
  float ss = fmaf(x0, x0, x1 * x1);
  #pragma unroll
  for (int m = 32; m >= 1; m >>= 1) ss += __shfl_xor(ss, m);
  const float sc = 1.0f / fmaxf(sqrtf(ss), 1e-12f);
  const unsigned short b0 = f2bf(x0 * sc), b1 = f2bf(x1 * sc);
  const unsigned pack = ((unsigned)b1 << 16) | (unsigned)b0;
  *(unsigned*)(Abf + (size_t)row * MD + colbase + lane * 2) = pack;
}

// ---- W f32 -> bf16 ----
__global__ void k_conv(const float* __restrict__ in, unsigned short* __restrict__ out,
                       int n4) {
  int i = blockIdx.x * blockDim.x + threadIdx.x;
  if (i >= n4) return;
  float4 v = ((const float4*)in)[i];
  ushort4 o;
  o.x = f2bf(v.x); o.y = f2bf(v.y); o.z = f2bf(v.z); o.w = f2bf(v.w);
  ((ushort4*)out)[i] = o;
}

// ---- emb f32 -> u0 bf16 = dinv[n] * emb[n] ----
__global__ void k_conv_emb(const float* __restrict__ emb, const float* __restrict__ dinv,
                           unsigned short* __restrict__ out) {
  int i = blockIdx.x * blockDim.x + threadIdx.x;
  if (i >= NN * DD / 4) return;
  const float d = dinv[i >> 5];  // 32 float4s per 128-wide row
  float4 v = ((const float4*)emb)[i];
  ushort4 o;
  o.x = f2bf(v.x * d); o.y = f2bf(v.y * d); o.z = f2bf(v.z * d); o.w = f2bf(v.w * d);
  ((ushort4*)out)[i] = o;
}

// ---- MFMA GEMM, BK=64, register prefetch: out = A @ W^T + b ----
__global__ __launch_bounds__(256) void k_gemm(const unsigned short* __restrict__ A,
                                              const unsigned short* __restrict__ B,
                                              const float* __restrict__ bias,
                                              float* __restrict__ out) {
  __shared__ unsigned short As[128][72];  // pad keeps conflicts ~prev level
  __shared__ unsigned short Bs[128][72];
  const int t = threadIdx.x;
  const int mt = blockIdx.x >> 2, nt = blockIdx.x & 3;
  const int i0 = mt * 128, j0 = nt * 128;
  const int lane = t & 63, wid = t >> 6;
  const int wr = wid >> 1, wc = wid & 1;    // 2x2 waves, 64x64 each
  const int fr = lane & 15, kg = lane >> 4;
  const int srow = t >> 1;                  // 128 rows, 2 threads/row
  const int sc0 = (t & 1) * 4;              // 4 float4 = half row (64B)
  const float4* pa = (const float4*)(A + (size_t)(i0 + srow) * MD);
  const float4* pb = (const float4*)(B + (size_t)(j0 + srow) * MD);
  f32x4 acc[4][4] = {};
  float4 ra[4], rb[4];
  #pragma unroll
  for (int q = 0; q < 4; ++q) { ra[q] = pa[sc0 + q]; rb[q] = pb[sc0 + q]; }
  for (int ks = 0; ks < 8; ++ks) {
    __syncthreads();
    #pragma unroll
    for (int q = 0; q < 4; ++q) {
      *(float4*)(&As[srow][(sc0 + q) * 8]) = ra[q];
      *(float4*)(&Bs[srow][(sc0 + q) * 8]) = rb[q];
    }
    __syncthreads();
    if (ks < 7) {
      #pragma unroll
      for (int q = 0; q < 4; ++q) {
        ra[q] = pa[(ks + 1) * 8 + sc0 + q];
        rb[q] = pb[(ks + 1) * 8 + sc0 + q];
      }
    }
    #pragma unroll
    for (int kk = 0; kk < 2; ++kk) {
      bf16x8 af[4], bb[4];
      #pragma unroll
      for (int m = 0; m < 4; ++m)
        af[m] = *(const bf16x8*)(&As[wr * 64 + m * 16 + fr][kk * 32 + kg * 8]);
      #pragma unroll
      for (int n = 0; n < 4; ++n)
        bb[n] = *(const bf16x8*)(&Bs[wc * 64 + n * 16 + fr][kk * 32 + kg * 8]);
      #pragma unroll
      for (int m = 0; m < 4; ++m)
        #pragma unroll
        for (int n = 0; n < 4; ++n)
          acc[m][n] = __builtin_amdgcn_mfma_f32_16x16x32_bf16(af[m], bb[n], acc[m][n], 0, 0, 0);
    }
  }
  #pragma unroll
  for (int n = 0; n < 4; ++n) {
    int col = j0 + wc * 64 + n * 16 + fr;
    float bv = bias[col];
    #pragma unroll
    for (int m = 0; m < 4; ++m) {
      int r0 = i0 + wr * 64 + m * 16 + kg * 4;
      #pragma unroll
      for (int r = 0; r < 4; ++r)
        out[(size_t)(r0 + r) * MD + col] = acc[m][n][r] + bv;
    }
  }
}

extern "C" void kernel_launch(void* const* d_in, const int* in_sizes, int n_in,
                              void* d_out, int out_size, void* d_ws, size_t ws_size,
                              hipStream_t stream) {
  const float* emb = (const float*)d_in[0];
  const int* ei = (const int*)d_in[1];
  const int* esrc = ei;                     // edge_index[0]
  const int* edst = ei + NE;                // edge_index[1]
  const int* send = (const int*)d_in[2];
  const int* recv = (const int*)d_in[3];
  const float* W = (const float*)d_in[4];
  const float* bias = (const float*)d_in[5];
  float* out = (float*)d_out;

  char* ws = (char*)d_ws;
  size_t off = 0;
  auto take = [&](size_t b) {
    char* p = ws + off;
    off = (off + b + 1023) & ~(size_t)1023;
    return p;
  };
  const size_t CSRN = (size_t)NE + 8 * (size_t)NN;  // padded CSR capacity
  int* zblk = (int*)take((size_t)(NBKT + 1 + NN) * 4);  // bcnt|lcnt|mark
  int* bcnt = zblk;
  int* lcnt = zblk + NBKT;
  int* mark = zblk + NBKT + 1;
  float* dinv = (float*)take((size_t)NN * 4);
  int* degI = (int*)take((size_t)NN * 4);
  int* rowstart = (int*)take((size_t)NN * 4);
  int* excl = (int*)take((size_t)NN * 4);
  int* bstart = (int*)take(NBKT * 4);
  int* gcursor = (int*)take(NBKT * 4);
  int* btot = (int*)take(NBKT * 4);
  int* bbase = (int*)take(NBKT * 4);
  int* list = (int*)take((size_t)MROWS * 4);
  unsigned* ebuf = (unsigned*)take((size_t)NE * 4);
  int* csr = (int*)take(CSRN * 4);
  unsigned short* x0 = (unsigned short*)take((size_t)(NN + 1) * DD * 2);
  unsigned short* x1 = (unsigned short*)take((size_t)(NN + 1) * DD * 2);
  unsigned short* x2 = (unsigned short*)take((size_t)(NN + 1) * DD * 2);
  unsigned short* Abf = (unsigned short*)take((size_t)MROWS * MD * 2);
  unsigned short* Wbf = (unsigned short*)take((size_t)MD * MD * 2);
  (void)ws_size; (void)in_sizes; (void)n_in; (void)out_size;

  hipMemsetAsync(zblk, 0, (size_t)(NBKT + 1 + NN) * 4, stream);

  // ---- CSR build: 2-level counting sort, streaming traffic only ----
  k_histo<<<1024, 256, 0, stream>>>(edst, bcnt);
  k_bscan<<<1, 256, 0, stream>>>(bcnt, gcursor, bstart);
  k_binA<<<(NE + TILE - 1) / TILE, 256, 0, stream>>>(esrc, edst, gcursor, ebuf);
  k_degB<<<NBKT, 256, 0, stream>>>(ebuf, bstart, bcnt, degI, dinv, excl, btot, x0, x1, x2);
  k_bscan2<<<1, 256, 0, stream>>>(btot, bbase);
  k_binB<<<NBKT, 256, 0, stream>>>(ebuf, bstart, bcnt, excl, bbase, btot, rowstart, csr);

  k_mark<<<(2 * SEL + 255) / 256, 256, 0, stream>>>(send, recv, mark);
  k_compact<<<(NN + 255) / 256, 256, 0, stream>>>(mark, list, lcnt);
  k_conv<<<(MD * MD / 4 + 255) / 256, 256, 0, stream>>>(W, Wbf, MD * MD / 4);
  k_conv_emb<<<(NN * DD / 4 + 255) / 256, 256, 0, stream>>>(emb, dinv, x0);

  // z1 slice from u0; 2 full layers; masked final layer (reuses x0)
  k_gnorm<<<MROWS / 4, 256, 0, stream>>>(send, recv, x0, Abf, 0);
  k_agg<<<2048, 256, 0, stream>>>(rowstart, degI, csr, dinv, x0, x1);
  k_gnorm<<<MROWS / 4, 256, 0, stream>>>(send, recv, x1, Abf, 128);
  k_agg<<<2048, 256, 0, stream>>>(rowstart, degI, csr, dinv, x1, x2);
  k_gnorm<<<MROWS / 4, 256, 0, stream>>>(send, recv, x2, Abf, 256);
  k_agg_list<<<1024, 256, 0, stream>>>(rowstart, degI, csr, dinv, x2, x0, list, lcnt);
  k_gnorm<<<MROWS / 4, 256, 0, stream>>>(send, recv, x0, Abf, 384);

  k_gemm<<<(MROWS / 128) * (MD / 128), 256, 0, stream>>>(Abf, Wbf, bias, out);
}

// Round 7
// 329.556 us; speedup vs baseline: 1.1818x; 1.1818x over previous
//
#include <hip/hip_runtime.h>

#define NN 100000      // nodes
#define NE 1600000     // edges
#define DD 128         // input dim (elements per row)
#define MD 512         // mlp dim = 128*4
#define SEL 16384      // senders count
#define MROWS 32768    // senders + receivers rows
#define NBKT 196       // buckets of 512 nodes
#define TILE 4096      // edges per k_binA block
#define SEGCAP 16384   // padded CSR slots per bucket (mean ~9984, hard cap)

typedef __attribute__((ext_vector_type(8))) short bf16x8;
typedef __attribute__((ext_vector_type(4))) float f32x4;

__device__ __forceinline__ unsigned short f2bf(float f) {
  unsigned u = __float_as_uint(f);
  u += 0x7fff + ((u >> 16) & 1);   // round-to-nearest-even
  return (unsigned short)(u >> 16);
}
__device__ __forceinline__ float bflo(unsigned v) { return __uint_as_float(v << 16); }
__device__ __forceinline__ float bfhi(unsigned v) { return __uint_as_float(v & 0xffff0000u); }

// ---- bucket histogram over dst (one streaming pass) ----
__global__ __launch_bounds__(256) void k_histo(const int* __restrict__ dst,
                                               int* __restrict__ bcnt) {
  __shared__ int h[NBKT];
  for (int i = threadIdx.x; i < NBKT; i += 256) h[i] = 0;
  __syncthreads();
  for (long e = blockIdx.x * 256L + threadIdx.x; e < NE; e += (long)gridDim.x * 256)
    atomicAdd(&h[dst[e] >> 9], 1);
  __syncthreads();
  for (int i = threadIdx.x; i < NBKT; i += 256)
    if (h[i]) atomicAdd(&bcnt[i], h[i]);
}

// ---- scan bucket counts -> bstart (ebuf layout) + live cursor ----
__global__ __launch_bounds__(256) void k_bscan(const int* __restrict__ bcnt,
                                               int* __restrict__ gcursor,
                                               int* __restrict__ bstart) {
  __shared__ int sm[256];
  int tid = threadIdx.x;
  int v = (tid < NBKT) ? bcnt[tid] : 0;
  sm[tid] = v;
  __syncthreads();
  for (int o = 1; o < 256; o <<= 1) {
    int t = (tid >= o) ? sm[tid - o] : 0;
    __syncthreads();
    sm[tid] += t;
    __syncthreads();
  }
  if (tid < NBKT) {
    int ex = sm[tid] - v;
    gcursor[tid] = ex;
    bstart[tid] = ex;
  }
}

// ---- bin edges by bucket: ebuf[slot] = src<<9 | (dst&511), bucket-contig ----
__global__ __launch_bounds__(256) void k_binA(const int* __restrict__ src,
                                              const int* __restrict__ dst,
                                              int* __restrict__ gcursor,
                                              unsigned* __restrict__ ebuf) {
  __shared__ int hist[NBKT];
  __shared__ int base[NBKT];
  __shared__ int cnt2[NBKT];
  const int tid = threadIdx.x;
  const long e0 = (long)blockIdx.x * TILE;
  for (int i = tid; i < NBKT; i += 256) { hist[i] = 0; cnt2[i] = 0; }
  __syncthreads();
  unsigned pk[16]; int bk[16];
  #pragma unroll
  for (int k = 0; k < 16; ++k) {
    const long e = e0 + k * 256 + tid;
    bk[k] = -1;
    if (e < NE) {
      const int d = dst[e], s = src[e];
      bk[k] = d >> 9;
      pk[k] = ((unsigned)s << 9) | (unsigned)(d & 511);
      atomicAdd(&hist[bk[k]], 1);
    }
  }
  __syncthreads();
  for (int i = tid; i < NBKT; i += 256)
    base[i] = atomicAdd(&gcursor[i], hist[i]);
  __syncthreads();
  #pragma unroll
  for (int k = 0; k < 16; ++k) {
    if (bk[k] >= 0) {
      const int lp = atomicAdd(&cnt2[bk[k]], 1);
      ebuf[base[bk[k]] + lp] = pk[k];
    }
  }
}

// ---- per-bucket degree + dinv + local padded-offset scan + bucket totals ----
__global__ __launch_bounds__(256) void k_degB(const unsigned* __restrict__ ebuf,
                                              const int* __restrict__ bstart,
                                              const int* __restrict__ bcnt,
                                              int* __restrict__ deg,
                                              float* __restrict__ dinv,
                                              int* __restrict__ excl,
                                              int* __restrict__ btot,
                                              unsigned short* __restrict__ x0,
                                              unsigned short* __restrict__ x1,
                                              unsigned short* __restrict__ x2) {
  __shared__ int ld[512];
  __shared__ int ps[256];
  const int b = blockIdx.x;
  const int n0 = b << 9;
  const int nn = min(512, NN - n0);
  const int tid = threadIdx.x;
  for (int i = tid; i < 512; i += 256) ld[i] = 0;
  __syncthreads();
  const int s0 = bstart[b], c = bcnt[b];
  for (int i = tid; i < c; i += 256) atomicAdd(&ld[ebuf[s0 + i] & 511], 1);
  __syncthreads();
  const int d0 = (tid * 2 < nn) ? ld[tid * 2] : 0;
  const int d1 = (tid * 2 + 1 < nn) ? ld[tid * 2 + 1] : 0;
  const int p0 = (d0 + 7) & ~7, p1 = (d1 + 7) & ~7;
  ps[tid] = p0 + p1;
  __syncthreads();
  for (int o = 1; o < 256; o <<= 1) {
    int t2 = (tid >= o) ? ps[tid - o] : 0;
    __syncthreads();
    ps[tid] += t2;
    __syncthreads();
  }
  const int exbase = ps[tid] - (p0 + p1);
  if (tid * 2 < nn) {
    deg[n0 + tid * 2] = d0;
    dinv[n0 + tid * 2] = rsqrtf(fmaxf((float)d0, 1.f));
    excl[n0 + tid * 2] = exbase;
  }
  if (tid * 2 + 1 < nn) {
    deg[n0 + tid * 2 + 1] = d1;
    dinv[n0 + tid * 2 + 1] = rsqrtf(fmaxf((float)d1, 1.f));
    excl[n0 + tid * 2 + 1] = exbase + p0;
  }
  if (tid == 255) btot[b] = ps[255];
  if (b == 0 && tid < 64) {  // zero the sentinel row NN of each x buffer
    ((unsigned*)(x0 + (size_t)NN * DD))[tid] = 0u;
    ((unsigned*)(x1 + (size_t)NN * DD))[tid] = 0u;
    ((unsigned*)(x2 + (size_t)NN * DD))[tid] = 0u;
  }
}

// ---- scan bucket padded totals -> bbase (csr layout) ----
__global__ __launch_bounds__(256) void k_bscan2(const int* __restrict__ btot,
                                                int* __restrict__ bbase) {
  __shared__ int sm[256];
  int tid = threadIdx.x;
  int v = (tid < NBKT) ? btot[tid] : 0;
  sm[tid] = v;
  __syncthreads();
  for (int o = 1; o < 256; o <<= 1) {
    int t = (tid >= o) ? sm[tid - o] : 0;
    __syncthreads();
    sm[tid] += t;
    __syncthreads();
  }
  if (tid < NBKT) bbase[tid] = sm[tid] - v;
}

// ---- per-bucket LDS scatter into padded CSR, coalesced out; pads=NN ----
__global__ __launch_bounds__(256) void k_binB(const unsigned* __restrict__ ebuf,
                                              const int* __restrict__ bstart,
                                              const int* __restrict__ bcnt,
                                              const int* __restrict__ excl,
                                              const int* __restrict__ bbase,
                                              const int* __restrict__ btot,
                                              int* __restrict__ rowstart,
                                              int* __restrict__ csr) {
  __shared__ int seg[SEGCAP];
  __shared__ int rs[512];
  __shared__ int cnt[512];
  const int b = blockIdx.x;
  const int n0 = b << 9;
  const int nn = min(512, NN - n0);
  const int seg0 = bbase[b];
  const int seglen = btot[b];
  for (int i = threadIdx.x; i < nn; i += 256) {
    const int ex = excl[n0 + i];
    rs[i] = ex;
    cnt[i] = 0;
    rowstart[n0 + i] = seg0 + ex;
  }
  for (int i = threadIdx.x; i < seglen; i += 256) seg[i] = NN;  // sentinel pad
  __syncthreads();
  const int s0 = bstart[b], c = bcnt[b];
  for (int i = threadIdx.x; i < c; i += 256) {
    const unsigned e = ebuf[s0 + i];
    const int dl = e & 511;
    const int pos = rs[dl] + atomicAdd(&cnt[dl], 1);
    seg[pos] = (int)(e >> 9);
  }
  __syncthreads();
  for (int i = threadIdx.x; i < seglen; i += 256) csr[seg0 + i] = seg[i];
}

// ---- mark + compact the nodes needed by the final layer ----
__global__ void k_mark(const int* __restrict__ sl, const int* __restrict__ rl,
                       int* __restrict__ mark) {
  int i = blockIdx.x * blockDim.x + threadIdx.x;
  if (i < SEL) mark[sl[i]] = 1;
  else if (i < 2 * SEL) mark[rl[i - SEL]] = 1;
}

__global__ void k_compact(const int* __restrict__ mark, int* __restrict__ list,
                          int* __restrict__ cnt) {
  int n = blockIdx.x * blockDim.x + threadIdx.x;
  if (n < NN && mark[n]) {
    int p = atomicAdd(cnt, 1);
    list[p] = n;
  }
}

// ---- per-node aggregation of u = dinv*x: 8 unpredicated gathers in flight ----
// u_next[d] = dinv[d]^2 * sum_{s in N(d)} u[s]; pad slots hit zeroed row NN.
__device__ __forceinline__ void agg_row(int n, int lane,
                                        const int* __restrict__ rowstart,
                                        const int* __restrict__ deg,
                                        const int* __restrict__ csr,
                                        const float* __restrict__ dinv,
                                        const unsigned short* __restrict__ xin,
                                        unsigned short* __restrict__ xout) {
  const int start = rowstart[n];
  const int cntp = (deg[n] + 7) & ~7;
  float ax[8], ay[8];
  #pragma unroll
  for (int u = 0; u < 8; ++u) { ax[u] = 0.f; ay[u] = 0.f; }
  for (int j = 0; j < cntp; j += 8) {
    const int4 e0 = *(const int4*)(csr + start + j);
    const int4 e1 = *(const int4*)(csr + start + j + 4);
    unsigned v[8];
    v[0] = ((const unsigned*)(xin + (size_t)e0.x * DD))[lane];
    v[1] = ((const unsigned*)(xin + (size_t)e0.y * DD))[lane];
    v[2] = ((const unsigned*)(xin + (size_t)e0.z * DD))[lane];
    v[3] = ((const unsigned*)(xin + (size_t)e0.w * DD))[lane];
    v[4] = ((const unsigned*)(xin + (size_t)e1.x * DD))[lane];
    v[5] = ((const unsigned*)(xin + (size_t)e1.y * DD))[lane];
    v[6] = ((const unsigned*)(xin + (size_t)e1.z * DD))[lane];
    v[7] = ((const unsigned*)(xin + (size_t)e1.w * DD))[lane];
    #pragma unroll
    for (int u = 0; u < 8; ++u) { ax[u] += bflo(v[u]); ay[u] += bfhi(v[u]); }
  }
  const float s = dinv[n] * dinv[n];
  const float rx = (((ax[0] + ax[1]) + (ax[2] + ax[3])) + ((ax[4] + ax[5]) + (ax[6] + ax[7]))) * s;
  const float ry = (((ay[0] + ay[1]) + (ay[2] + ay[3])) + ((ay[4] + ay[5]) + (ay[6] + ay[7]))) * s;
  ((unsigned*)(xout + (size_t)n * DD))[lane] = ((unsigned)f2bf(ry) << 16) | (unsigned)f2bf(rx);
}

__global__ __launch_bounds__(256) void k_agg(const int* __restrict__ rowstart,
                                             const int* __restrict__ deg,
                                             const int* __restrict__ csr,
                                             const float* __restrict__ dinv,
                                             const unsigned short* __restrict__ xin,
                                             unsigned short* __restrict__ xout) {
  const int lane = threadIdx.x & 63;
  const int wid = (blockIdx.x * blockDim.x + threadIdx.x) >> 6;
  const int nw = (gridDim.x * blockDim.x) >> 6;
  for (int n = wid; n < NN; n += nw)
    agg_row(n, lane, rowstart, deg, csr, dinv, xin, xout);
}

__global__ __launch_bounds__(256) void k_agg_list(const int* __restrict__ rowstart,
                                                  const int* __restrict__ deg,
                                                  const int* __restrict__ csr,
                                                  const float* __restrict__ dinv,
                                                  const unsigned short* __restrict__ xin,
                                                  unsigned short* __restrict__ xout,
                                                  const int* __restrict__ list,
                                                  const int* __restrict__ lcnt) {
  const int lane = threadIdx.x & 63;
  const int wid = (blockIdx.x * blockDim.x + threadIdx.x) >> 6;
  const int nw = (gridDim.x * blockDim.x) >> 6;
  const int cl = *lcnt;
  for (int i = wid; i < cl; i += nw)
    agg_row(list[i], lane, rowstart, deg, csr, dinv, xin, xout);
}

// ---- gather + l2-normalize selected bf16 rows -> bf16 A-matrix slice ----
__global__ __launch_bounds__(256) void k_gnorm(const int* __restrict__ sl,
                                               const int* __restrict__ rl,
                                               const unsigned short* __restrict__ xin,
                                               unsigned short* __restrict__ Abf,
                                               int colbase) {
  const int lane = threadIdx.x & 63;
  const int row = blockIdx.x * 4 + (threadIdx.x >> 6);
  if (row >= MROWS) return;
  const int node = (row < SEL) ? sl[row] : rl[row - SEL];
  const unsigned v = ((const unsigned*)(xin + (size_t)node * DD))[lane];
  const float x0 = bflo(v), x1 = bfhi(v);
  float ss = fmaf(x0, x0, x1 * x1);
  #pragma unroll
  for (int m = 32; m >= 1; m >>= 1) ss += __shfl_xor(ss, m);
  const float sc = 1.0f / fmaxf(sqrtf(ss), 1e-12f);
  const unsigned short b0 = f2bf(x0 * sc), b1 = f2bf(x1 * sc);
  const unsigned pack = ((unsigned)b1 << 16) | (unsigned)b0;
  *(unsigned*)(Abf + (size_t)row * MD + colbase + lane * 2) = pack;
}

// ---- W f32 -> bf16 ----
__global__ void k_conv(const float* __restrict__ in, unsigned short* __restrict__ out,
                       int n4) {
  int i = blockIdx.x * blockDim.x + threadIdx.x;
  if (i >= n4) return;
  float4 v = ((const float4*)in)[i];
  ushort4 o;
  o.x = f2bf(v.x); o.y = f2bf(v.y); o.z = f2bf(v.z); o.w = f2bf(v.w);
  ((ushort4*)out)[i] = o;
}

// ---- emb f32 -> u0 bf16 = dinv[n] * emb[n] ----
__global__ void k_conv_emb(const float* __restrict__ emb, const float* __restrict__ dinv,
                           unsigned short* __restrict__ out) {
  int i = blockIdx.x * blockDim.x + threadIdx.x;
  if (i >= NN * DD / 4) return;
  const float d = dinv[i >> 5];  // 32 float4s per 128-wide row
  float4 v = ((const float4*)emb)[i];
  ushort4 o;
  o.x = f2bf(v.x * d); o.y = f2bf(v.y * d); o.z = f2bf(v.z * d); o.w = f2bf(v.w * d);
  ((ushort4*)out)[i] = o;
}

// ---- MFMA GEMM (round-5 k-loop) + XCD swizzle + LDS-staged epilogue ----
// out[i][j] = sum_k A[i][k]*W[j][k] + bias[j]
__global__ __launch_bounds__(256) void k_gemm(const unsigned short* __restrict__ A,
                                              const unsigned short* __restrict__ B,
                                              const float* __restrict__ bias,
                                              float* __restrict__ out) {
  __shared__ __align__(16) char smraw[20480];
  unsigned short (*As)[40] = (unsigned short(*)[40])smraw;            // 10240 B
  unsigned short (*Bs)[40] = (unsigned short(*)[40])(smraw + 10240);  // 10240 B
  float (*et)[132] = (float(*)[132])smraw;                            // 16896 B (epilogue)
  const int t = threadIdx.x;
  // XCD swizzle: round-robin dispatch puts bid%8 on one XCD; give that XCD a
  // contiguous mt range with its 4 nt-siblings adjacent in time.
  const int bid = blockIdx.x;
  const int xcd = bid & 7;
  const int j = bid >> 3;               // 0..127
  const int mt = xcd * 32 + (j >> 2);   // 0..255
  const int nt = j & 3;
  const int i0 = mt * 128, j0 = nt * 128;
  const int lane = t & 63, wid = t >> 6;
  const int wr = wid >> 1, wc = wid & 1;    // 2x2 waves, 64x64 each
  const int fr = lane & 15, kg = lane >> 4; // fragment row/col, k-group
  f32x4 acc[4][4] = {};
  for (int k0 = 0; k0 < MD; k0 += 32) {
    #pragma unroll
    for (int rep = 0; rep < 2; ++rep) {
      int id = t + rep * 256;
      int row = id >> 2, seg = id & 3;  // 128 rows x 4 segs of 8 bf16
      float4 va = *(const float4*)(A + (size_t)(i0 + row) * MD + k0 + seg * 8);
      *(float4*)(&As[row][seg * 8]) = va;
      float4 vb = *(const float4*)(B + (size_t)(j0 + row) * MD + k0 + seg * 8);
      *(float4*)(&Bs[row][seg * 8]) = vb;
    }
    __syncthreads();
    bf16x8 af[4], bfr[4];
    #pragma unroll
    for (int m = 0; m < 4; ++m)
      af[m] = *(const bf16x8*)(&As[wr * 64 + m * 16 + fr][kg * 8]);
    #pragma unroll
    for (int n = 0; n < 4; ++n)
      bfr[n] = *(const bf16x8*)(&Bs[wc * 64 + n * 16 + fr][kg * 8]);
    #pragma unroll
    for (int m = 0; m < 4; ++m)
      #pragma unroll
      for (int n = 0; n < 4; ++n)
        acc[m][n] = __builtin_amdgcn_mfma_f32_16x16x32_bf16(af[m], bfr[n], acc[m][n], 0, 0, 0);
    __syncthreads();
  }
  // epilogue: per m-chunk stage 32x128 f32 in LDS, write 512B-contiguous rows
  #pragma unroll
  for (int m = 0; m < 4; ++m) {
    __syncthreads();
    #pragma unroll
    for (int n = 0; n < 4; ++n)
      #pragma unroll
      for (int r = 0; r < 4; ++r)
        et[wr * 16 + kg * 4 + r][wc * 64 + n * 16 + fr] = acc[m][n][r];
    __syncthreads();
    #pragma unroll
    for (int w = 0; w < 4; ++w) {
      const int idx = w * 256 + t;
      const int lrow = idx >> 5, lc4 = idx & 31;
      const int grow = i0 + (lrow >> 4) * 64 + m * 16 + (lrow & 15);
      const int gcol = j0 + lc4 * 4;
      const float4 bv = *(const float4*)(bias + gcol);
      float4 o;
      o.x = et[lrow][lc4 * 4 + 0] + bv.x;
      o.y = et[lrow][lc4 * 4 + 1] + bv.y;
      o.z = et[lrow][lc4 * 4 + 2] + bv.z;
      o.w = et[lrow][lc4 * 4 + 3] + bv.w;
      *(float4*)(out + (size_t)grow * MD + gcol) = o;
    }
  }
}

extern "C" void kernel_launch(void* const* d_in, const int* in_sizes, int n_in,
                              void* d_out, int out_size, void* d_ws, size_t ws_size,
                              hipStream_t stream) {
  const float* emb = (const float*)d_in[0];
  const int* ei = (const int*)d_in[1];
  const int* esrc = ei;                     // edge_index[0]
  const int* edst = ei + NE;                // edge_index[1]
  const int* send = (const int*)d_in[2];
  const int* recv = (const int*)d_in[3];
  const float* W = (const float*)d_in[4];
  const float* bias = (const float*)d_in[5];
  float* out = (float*)d_out;

  char* ws = (char*)d_ws;
  size_t off = 0;
  auto take = [&](size_t b) {
    char* p = ws + off;
    off = (off + b + 1023) & ~(size_t)1023;
    return p;
  };
  const size_t CSRN = (size_t)NE + 8 * (size_t)NN;  // padded CSR capacity
  int* zblk = (int*)take((size_t)(NBKT + 1 + NN) * 4);  // bcnt|lcnt|mark
  int* bcnt = zblk;
  int* lcnt = zblk + NBKT;
  int* mark = zblk + NBKT + 1;
  float* dinv = (float*)take((size_t)NN * 4);
  int* degI = (int*)take((size_t)NN * 4);
  int* rowstart = (int*)take((size_t)NN * 4);
  int* excl = (int*)take((size_t)NN * 4);
  int* bstart = (int*)take(NBKT * 4);
  int* gcursor = (int*)take(NBKT * 4);
  int* btot = (int*)take(NBKT * 4);
  int* bbase = (int*)take(NBKT * 4);
  int* list = (int*)take((size_t)MROWS * 4);
  unsigned* ebuf = (unsigned*)take((size_t)NE * 4);
  int* csr = (int*)take(CSRN * 4);
  unsigned short* x0 = (unsigned short*)take((size_t)(NN + 1) * DD * 2);
  unsigned short* x1 = (unsigned short*)take((size_t)(NN + 1) * DD * 2);
  unsigned short* x2 = (unsigned short*)take((size_t)(NN + 1) * DD * 2);
  unsigned short* Abf = (unsigned short*)take((size_t)MROWS * MD * 2);
  unsigned short* Wbf = (unsigned short*)take((size_t)MD * MD * 2);
  (void)ws_size; (void)in_sizes; (void)n_in; (void)out_size;

  hipMemsetAsync(zblk, 0, (size_t)(NBKT + 1 + NN) * 4, stream);

  // ---- CSR build: 2-level counting sort, streaming traffic only ----
  k_histo<<<1024, 256, 0, stream>>>(edst, bcnt);
  k_bscan<<<1, 256, 0, stream>>>(bcnt, gcursor, bstart);
  k_binA<<<(NE + TILE - 1) / TILE, 256, 0, stream>>>(esrc, edst, gcursor, ebuf);
  k_degB<<<NBKT, 256, 0, stream>>>(ebuf, bstart, bcnt, degI, dinv, excl, btot, x0, x1, x2);
  k_bscan2<<<1, 256, 0, stream>>>(btot, bbase);
  k_binB<<<NBKT, 256, 0, stream>>>(ebuf, bstart, bcnt, excl, bbase, btot, rowstart, csr);

  k_mark<<<(2 * SEL + 255) / 256, 256, 0, stream>>>(send, recv, mark);
  k_compact<<<(NN + 255) / 256, 256, 0, stream>>>(mark, list, lcnt);
  k_conv<<<(MD * MD / 4 + 255) / 256, 256, 0, stream>>>(W, Wbf, MD * MD / 4);
  k_conv_emb<<<(NN * DD / 4 + 255) / 256, 256, 0, stream>>>(emb, dinv, x0);

  // z1 slice from u0; 2 full layers; masked final layer (reuses x0)
  k_gnorm<<<MROWS / 4, 256, 0, stream>>>(send, recv, x0, Abf, 0);
  k_agg<<<2048, 256, 0, stream>>>(rowstart, degI, csr, dinv, x0, x1);
  k_gnorm<<<MROWS / 4, 256, 0, stream>>>(send, recv, x1, Abf, 128);
  k_agg<<<2048, 256, 0, stream>>>(rowstart, degI, csr, dinv, x1, x2);
  k_gnorm<<<MROWS / 4, 256, 0, stream>>>(send, recv, x2, Abf, 256);
  k_agg_list<<<1024, 256, 0, stream>>>(rowstart, degI, csr, dinv, x2, x0, list, lcnt);
  k_gnorm<<<MROWS / 4, 256, 0, stream>>>(send, recv, x0, Abf, 384);

  k_gemm<<<(MROWS / 128) * (MD / 128), 256, 0, stream>>>(Abf, Wbf, bias, out);
}

// Round 8
// 321.446 us; speedup vs baseline: 1.2116x; 1.0252x over previous
//
#include <hip/hip_runtime.h>

#define NN 100000      // nodes
#define NE 1600000     // edges
#define DD 128         // input dim (elements per row)
#define MD 512         // mlp dim = 128*4
#define SEL 16384      // senders count
#define MROWS 32768    // senders + receivers rows
#define NBKT 196       // buckets of 512 nodes
#define TILE 4096      // edges per k_binA block
#define SEGCAP 16384   // padded CSR slots per bucket

typedef __attribute__((ext_vector_type(8))) short bf16x8;
typedef __attribute__((ext_vector_type(4))) float f32x4;

__device__ __forceinline__ unsigned short f2bf(float f) {
  unsigned u = __float_as_uint(f);
  u += 0x7fff + ((u >> 16) & 1);   // round-to-nearest-even
  return (unsigned short)(u >> 16);
}
__device__ __forceinline__ float bflo(unsigned v) { return __uint_as_float(v << 16); }
__device__ __forceinline__ float bfhi(unsigned v) { return __uint_as_float(v & 0xffff0000u); }

// ---- bucket histogram over dst (one streaming pass) ----
__global__ __launch_bounds__(256) void k_histo(const int* __restrict__ dst,
                                               int* __restrict__ bcnt) {
  __shared__ int h[NBKT];
  for (int i = threadIdx.x; i < NBKT; i += 256) h[i] = 0;
  __syncthreads();
  for (long e = blockIdx.x * 256L + threadIdx.x; e < NE; e += (long)gridDim.x * 256)
    atomicAdd(&h[dst[e] >> 9], 1);
  __syncthreads();
  for (int i = threadIdx.x; i < NBKT; i += 256)
    if (h[i]) atomicAdd(&bcnt[i], h[i]);
}

// ---- scan bucket counts -> bstart (ebuf layout) + live cursor ----
__global__ __launch_bounds__(256) void k_bscan(const int* __restrict__ bcnt,
                                               int* __restrict__ gcursor,
                                               int* __restrict__ bstart) {
  __shared__ int sm[256];
  int tid = threadIdx.x;
  int v = (tid < NBKT) ? bcnt[tid] : 0;
  sm[tid] = v;
  __syncthreads();
  for (int o = 1; o < 256; o <<= 1) {
    int t = (tid >= o) ? sm[tid - o] : 0;
    __syncthreads();
    sm[tid] += t;
    __syncthreads();
  }
  if (tid < NBKT) {
    int ex = sm[tid] - v;
    gcursor[tid] = ex;
    bstart[tid] = ex;
  }
}

// ---- bin edges by bucket: ebuf[slot] = src<<9 | (dst&511), bucket-contig ----
__global__ __launch_bounds__(256) void k_binA(const int* __restrict__ src,
                                              const int* __restrict__ dst,
                                              int* __restrict__ gcursor,
                                              unsigned* __restrict__ ebuf) {
  __shared__ int hist[NBKT];
  __shared__ int base[NBKT];
  __shared__ int cnt2[NBKT];
  const int tid = threadIdx.x;
  const long e0 = (long)blockIdx.x * TILE;
  for (int i = tid; i < NBKT; i += 256) { hist[i] = 0; cnt2[i] = 0; }
  __syncthreads();
  unsigned pk[16]; int bk[16];
  #pragma unroll
  for (int k = 0; k < 16; ++k) {
    const long e = e0 + k * 256 + tid;
    bk[k] = -1;
    if (e < NE) {
      const int d = dst[e], s = src[e];
      bk[k] = d >> 9;
      pk[k] = ((unsigned)s << 9) | (unsigned)(d & 511);
      atomicAdd(&hist[bk[k]], 1);
    }
  }
  __syncthreads();
  for (int i = tid; i < NBKT; i += 256)
    base[i] = atomicAdd(&gcursor[i], hist[i]);
  __syncthreads();
  #pragma unroll
  for (int k = 0; k < 16; ++k) {
    if (bk[k] >= 0) {
      const int lp = atomicAdd(&cnt2[bk[k]], 1);
      ebuf[base[bk[k]] + lp] = pk[k];
    }
  }
}

// ---- per-bucket degree + dinv + local padded-offset scan + bucket totals ----
__global__ __launch_bounds__(256) void k_degB(const unsigned* __restrict__ ebuf,
                                              const int* __restrict__ bstart,
                                              const int* __restrict__ bcnt,
                                              int* __restrict__ deg,
                                              float* __restrict__ dinv,
                                              int* __restrict__ excl,
                                              int* __restrict__ btot,
                                              unsigned short* __restrict__ x0,
                                              unsigned short* __restrict__ x1,
                                              unsigned short* __restrict__ x2) {
  __shared__ int ld[512];
  __shared__ int ps[256];
  const int b = blockIdx.x;
  const int n0 = b << 9;
  const int nn = min(512, NN - n0);
  const int tid = threadIdx.x;
  for (int i = tid; i < 512; i += 256) ld[i] = 0;
  __syncthreads();
  const int s0 = bstart[b], c = bcnt[b];
  for (int i = tid; i < c; i += 256) atomicAdd(&ld[ebuf[s0 + i] & 511], 1);
  __syncthreads();
  const int d0 = (tid * 2 < nn) ? ld[tid * 2] : 0;
  const int d1 = (tid * 2 + 1 < nn) ? ld[tid * 2 + 1] : 0;
  const int p0 = (d0 + 7) & ~7, p1 = (d1 + 7) & ~7;
  ps[tid] = p0 + p1;
  __syncthreads();
  for (int o = 1; o < 256; o <<= 1) {
    int t2 = (tid >= o) ? ps[tid - o] : 0;
    __syncthreads();
    ps[tid] += t2;
    __syncthreads();
  }
  const int exbase = ps[tid] - (p0 + p1);
  if (tid * 2 < nn) {
    deg[n0 + tid * 2] = d0;
    dinv[n0 + tid * 2] = rsqrtf(fmaxf((float)d0, 1.f));
    excl[n0 + tid * 2] = exbase;
  }
  if (tid * 2 + 1 < nn) {
    deg[n0 + tid * 2 + 1] = d1;
    dinv[n0 + tid * 2 + 1] = rsqrtf(fmaxf((float)d1, 1.f));
    excl[n0 + tid * 2 + 1] = exbase + p0;
  }
  if (tid == 255) btot[b] = ps[255];
  if (b == 0 && tid < 64) {  // zero the sentinel row NN of each x buffer
    ((unsigned*)(x0 + (size_t)NN * DD))[tid] = 0u;
    ((unsigned*)(x1 + (size_t)NN * DD))[tid] = 0u;
    ((unsigned*)(x2 + (size_t)NN * DD))[tid] = 0u;
  }
}

// ---- scan bucket padded totals -> bbase (csr layout) ----
__global__ __launch_bounds__(256) void k_bscan2(const int* __restrict__ btot,
                                                int* __restrict__ bbase) {
  __shared__ int sm[256];
  int tid = threadIdx.x;
  int v = (tid < NBKT) ? btot[tid] : 0;
  sm[tid] = v;
  __syncthreads();
  for (int o = 1; o < 256; o <<= 1) {
    int t = (tid >= o) ? sm[tid - o] : 0;
    __syncthreads();
    sm[tid] += t;
    __syncthreads();
  }
  if (tid < NBKT) bbase[tid] = sm[tid] - v;
}

// ---- per-bucket LDS scatter into padded CSR, coalesced out; pads=NN ----
__global__ __launch_bounds__(256) void k_binB(const unsigned* __restrict__ ebuf,
                                              const int* __restrict__ bstart,
                                              const int* __restrict__ bcnt,
                                              const int* __restrict__ excl,
                                              const int* __restrict__ bbase,
                                              const int* __restrict__ btot,
                                              int* __restrict__ rowstart,
                                              int* __restrict__ csr) {
  __shared__ int seg[SEGCAP];
  __shared__ int rs[512];
  __shared__ int cnt[512];
  const int b = blockIdx.x;
  const int n0 = b << 9;
  const int nn = min(512, NN - n0);
  const int seg0 = bbase[b];
  const int seglen = btot[b];
  for (int i = threadIdx.x; i < nn; i += 256) {
    const int ex = excl[n0 + i];
    rs[i] = ex;
    cnt[i] = 0;
    rowstart[n0 + i] = seg0 + ex;
  }
  for (int i = threadIdx.x; i < seglen; i += 256) seg[i] = NN;  // sentinel pad
  __syncthreads();
  const int s0 = bstart[b], c = bcnt[b];
  for (int i = threadIdx.x; i < c; i += 256) {
    const unsigned e = ebuf[s0 + i];
    const int dl = e & 511;
    const int pos = rs[dl] + atomicAdd(&cnt[dl], 1);
    seg[pos] = (int)(e >> 9);
  }
  __syncthreads();
  for (int i = threadIdx.x; i < seglen; i += 256) csr[seg0 + i] = seg[i];
}

// ---- mark + compact + unique-index the nodes needed by z-gather ----
__global__ void k_mark(const int* __restrict__ sl, const int* __restrict__ rl,
                       int* __restrict__ mark) {
  int i = blockIdx.x * blockDim.x + threadIdx.x;
  if (i < SEL) mark[sl[i]] = 1;
  else if (i < 2 * SEL) mark[rl[i - SEL]] = 1;
}

__global__ void k_compact(const int* __restrict__ mark, int* __restrict__ list,
                          int* __restrict__ cnt, int* __restrict__ uidx) {
  int n = blockIdx.x * blockDim.x + threadIdx.x;
  if (n < NN && mark[n]) {
    int p = atomicAdd(cnt, 1);
    list[p] = n;
    uidx[n] = p;
  }
}

__global__ void k_rowmap(const int* __restrict__ sl, const int* __restrict__ rl,
                         const int* __restrict__ uidx, int* __restrict__ rowmap) {
  int i = blockIdx.x * blockDim.x + threadIdx.x;
  if (i >= MROWS) return;
  const int node = (i < SEL) ? sl[i] : rl[i - SEL];
  rowmap[i] = uidx[node];
}

// ---- fused aggregation (+ optional z-normalize write) ----
// u_next[d] = dinv[d]^2 * sum_{s in N(d)} u[s]; 8B/lane gathers, 2 edges/load.
// Marked nodes also get z = normalize(u_next) written to zbuf slice.
template<int WX>
__global__ __launch_bounds__(256) void k_aggf(const int* __restrict__ rowstart,
                                              const int* __restrict__ deg,
                                              const int* __restrict__ csr,
                                              const float* __restrict__ dinv,
                                              const unsigned short* __restrict__ xin,
                                              unsigned short* __restrict__ xout,
                                              unsigned short* __restrict__ zbuf,
                                              const int* __restrict__ uidx,
                                              int zcol,
                                              const int* __restrict__ list,
                                              const int* __restrict__ lcnt) {
  const int lane = threadIdx.x & 63;
  const int half = lane >> 5, l5 = lane & 31;
  const int wid = (blockIdx.x * blockDim.x + threadIdx.x) >> 6;
  const int nw = (gridDim.x * blockDim.x) >> 6;
  const int total = WX ? NN : *lcnt;
  for (int it = wid; it < total; it += nw) {
    const int n = WX ? it : list[it];
    const int start = rowstart[n];
    const int cntp = (deg[n] + 7) & ~7;
    float a0 = 0.f, a1 = 0.f, a2 = 0.f, a3 = 0.f;
    float b0 = 0.f, b1 = 0.f, b2 = 0.f, b3 = 0.f;
    for (int j = 0; j < cntp; j += 8) {
      const int4 e0 = *(const int4*)(csr + start + j);
      const int4 e1 = *(const int4*)(csr + start + j + 4);
      const int i0 = half ? e0.y : e0.x;
      const int i1 = half ? e0.w : e0.z;
      const int i2 = half ? e1.y : e1.x;
      const int i3 = half ? e1.w : e1.z;
      const uint2 v0 = *(const uint2*)(xin + (size_t)i0 * DD + l5 * 4);
      const uint2 v1 = *(const uint2*)(xin + (size_t)i1 * DD + l5 * 4);
      const uint2 v2 = *(const uint2*)(xin + (size_t)i2 * DD + l5 * 4);
      const uint2 v3 = *(const uint2*)(xin + (size_t)i3 * DD + l5 * 4);
      a0 += bflo(v0.x); a1 += bfhi(v0.x); a2 += bflo(v0.y); a3 += bfhi(v0.y);
      b0 += bflo(v1.x); b1 += bfhi(v1.x); b2 += bflo(v1.y); b3 += bfhi(v1.y);
      a0 += bflo(v2.x); a1 += bfhi(v2.x); a2 += bflo(v2.y); a3 += bfhi(v2.y);
      b0 += bflo(v3.x); b1 += bfhi(v3.x); b2 += bflo(v3.y); b3 += bfhi(v3.y);
    }
    const float s = dinv[n] * dinv[n];
    float t0 = (a0 + b0) * s, t1 = (a1 + b1) * s;
    float t2 = (a2 + b2) * s, t3 = (a3 + b3) * s;
    t0 += __shfl_xor(t0, 32); t1 += __shfl_xor(t1, 32);
    t2 += __shfl_xor(t2, 32); t3 += __shfl_xor(t3, 32);
    // lane l (both halves identical) holds elems [l5*4 .. l5*4+3]
    if (WX) {
      const unsigned plo = ((unsigned)f2bf(t1) << 16) | f2bf(t0);
      const unsigned phi = ((unsigned)f2bf(t3) << 16) | f2bf(t2);
      *(unsigned*)(xout + (size_t)n * DD + l5 * 4 + half * 2) = half ? phi : plo;
    }
    const int uz = uidx[n];
    if (uz >= 0) {
      float ss = fmaf(t0, t0, fmaf(t1, t1, fmaf(t2, t2, t3 * t3)));
      #pragma unroll
      for (int m = 16; m >= 1; m >>= 1) ss += __shfl_xor(ss, m);
      const float sc = 1.0f / fmaxf(sqrtf(ss), 1e-12f);
      const unsigned zlo = ((unsigned)f2bf(t1 * sc) << 16) | f2bf(t0 * sc);
      const unsigned zhi = ((unsigned)f2bf(t3 * sc) << 16) | f2bf(t2 * sc);
      *(unsigned*)(zbuf + (size_t)uz * MD + zcol + l5 * 4 + half * 2) = half ? zhi : zlo;
    }
  }
}

// ---- W f32 -> bf16 ----
__global__ void k_conv(const float* __restrict__ in, unsigned short* __restrict__ out,
                       int n4) {
  int i = blockIdx.x * blockDim.x + threadIdx.x;
  if (i >= n4) return;
  float4 v = ((const float4*)in)[i];
  ushort4 o;
  o.x = f2bf(v.x); o.y = f2bf(v.y); o.z = f2bf(v.z); o.w = f2bf(v.w);
  ((ushort4*)out)[i] = o;
}

// ---- emb f32 -> u0 bf16 = dinv*emb, fused z0 = normalize(emb) for marked ----
__global__ __launch_bounds__(256) void k_conv_emb2(const float* __restrict__ emb,
                                                   const float* __restrict__ dinv,
                                                   const int* __restrict__ uidx,
                                                   unsigned short* __restrict__ x0,
                                                   unsigned short* __restrict__ zbuf) {
  const int lane = threadIdx.x & 63;
  const int n = blockIdx.x * 4 + (threadIdx.x >> 6);
  if (n >= NN) return;
  const float2 v = ((const float2*)(emb + (size_t)n * DD))[lane];
  const float d = dinv[n];
  *(unsigned*)(x0 + (size_t)n * DD + lane * 2) =
      ((unsigned)f2bf(v.y * d) << 16) | f2bf(v.x * d);
  const int uz = uidx[n];
  if (uz >= 0) {
    float ss = fmaf(v.x, v.x, v.y * v.y);
    #pragma unroll
    for (int m = 32; m >= 1; m >>= 1) ss += __shfl_xor(ss, m);
    const float sc = 1.0f / fmaxf(sqrtf(ss), 1e-12f);
    *(unsigned*)(zbuf + (size_t)uz * MD + lane * 2) =
        ((unsigned)f2bf(v.y * sc) << 16) | f2bf(v.x * sc);
  }
}

// ---- MFMA GEMM, indirect A rows from zbuf, XCD swizzle, LDS epilogue ----
// out[i][j] = sum_k zbuf[rowmap[i]][k] * W[j][k] + bias[j]
__global__ __launch_bounds__(256) void k_gemm(const unsigned short* __restrict__ zbuf,
                                              const int* __restrict__ rowmap,
                                              const unsigned short* __restrict__ B,
                                              const float* __restrict__ bias,
                                              float* __restrict__ out) {
  __shared__ __align__(16) char smraw[20480];
  unsigned short (*As)[40] = (unsigned short(*)[40])smraw;            // 10240 B
  unsigned short (*Bs)[40] = (unsigned short(*)[40])(smraw + 10240);  // 10240 B
  float (*et)[132] = (float(*)[132])smraw;                            // 16896 B
  const int t = threadIdx.x;
  const int bid = blockIdx.x;
  const int xcd = bid & 7;
  const int j = bid >> 3;
  const int mt = xcd * 32 + (j >> 2);
  const int nt = j & 3;
  const int i0 = mt * 128, j0 = nt * 128;
  const int lane = t & 63, wid = t >> 6;
  const int wr = wid >> 1, wc = wid & 1;
  const int fr = lane & 15, kg = lane >> 4;
  const int srow = t >> 2, seg = t & 3;
  const unsigned short* pa0 = zbuf + (size_t)rowmap[i0 + srow] * MD + seg * 8;
  const unsigned short* pa1 = zbuf + (size_t)rowmap[i0 + srow + 64] * MD + seg * 8;
  const unsigned short* pb0 = B + (size_t)(j0 + srow) * MD + seg * 8;
  const unsigned short* pb1 = B + (size_t)(j0 + srow + 64) * MD + seg * 8;
  f32x4 acc[4][4] = {};
  for (int k0 = 0; k0 < MD; k0 += 32) {
    *(float4*)(&As[srow][seg * 8]) = *(const float4*)(pa0 + k0);
    *(float4*)(&As[srow + 64][seg * 8]) = *(const float4*)(pa1 + k0);
    *(float4*)(&Bs[srow][seg * 8]) = *(const float4*)(pb0 + k0);
    *(float4*)(&Bs[srow + 64][seg * 8]) = *(const float4*)(pb1 + k0);
    __syncthreads();
    bf16x8 af[4], bfr[4];
    #pragma unroll
    for (int m = 0; m < 4; ++m)
      af[m] = *(const bf16x8*)(&As[wr * 64 + m * 16 + fr][kg * 8]);
    #pragma unroll
    for (int n = 0; n < 4; ++n)
      bfr[n] = *(const bf16x8*)(&Bs[wc * 64 + n * 16 + fr][kg * 8]);
    #pragma unroll
    for (int m = 0; m < 4; ++m)
      #pragma unroll
      for (int n = 0; n < 4; ++n)
        acc[m][n] = __builtin_amdgcn_mfma_f32_16x16x32_bf16(af[m], bfr[n], acc[m][n], 0, 0, 0);
    __syncthreads();
  }
  // epilogue: per m-chunk stage 32x128 f32 in LDS, write 512B-contiguous rows
  #pragma unroll
  for (int m = 0; m < 4; ++m) {
    __syncthreads();
    #pragma unroll
    for (int n = 0; n < 4; ++n)
      #pragma unroll
      for (int r = 0; r < 4; ++r)
        et[wr * 16 + kg * 4 + r][wc * 64 + n * 16 + fr] = acc[m][n][r];
    __syncthreads();
    #pragma unroll
    for (int w = 0; w < 4; ++w) {
      const int idx = w * 256 + t;
      const int lrow = idx >> 5, lc4 = idx & 31;
      const int grow = i0 + (lrow >> 4) * 64 + m * 16 + (lrow & 15);
      const int gcol = j0 + lc4 * 4;
      const float4 bv = *(const float4*)(bias + gcol);
      float4 o;
      o.x = et[lrow][lc4 * 4 + 0] + bv.x;
      o.y = et[lrow][lc4 * 4 + 1] + bv.y;
      o.z = et[lrow][lc4 * 4 + 2] + bv.z;
      o.w = et[lrow][lc4 * 4 + 3] + bv.w;
      *(float4*)(out + (size_t)grow * MD + gcol) = o;
    }
  }
}

extern "C" void kernel_launch(void* const* d_in, const int* in_sizes, int n_in,
                              void* d_out, int out_size, void* d_ws, size_t ws_size,
                              hipStream_t stream) {
  const float* emb = (const float*)d_in[0];
  const int* ei = (const int*)d_in[1];
  const int* esrc = ei;                     // edge_index[0]
  const int* edst = ei + NE;                // edge_index[1]
  const int* send = (const int*)d_in[2];
  const int* recv = (const int*)d_in[3];
  const float* W = (const float*)d_in[4];
  const float* bias = (const float*)d_in[5];
  float* out = (float*)d_out;

  char* ws = (char*)d_ws;
  size_t off = 0;
  auto take = [&](size_t b) {
    char* p = ws + off;
    off = (off + b + 1023) & ~(size_t)1023;
    return p;
  };
  const size_t CSRN = (size_t)NE + 8 * (size_t)NN;  // padded CSR capacity
  int* zblk = (int*)take((size_t)(NBKT + 1 + NN) * 4);  // bcnt|lcnt|mark
  int* bcnt = zblk;
  int* lcnt = zblk + NBKT;
  int* mark = zblk + NBKT + 1;
  int* uidx = (int*)take((size_t)NN * 4);
  float* dinv = (float*)take((size_t)NN * 4);
  int* degI = (int*)take((size_t)NN * 4);
  int* rowstart = (int*)take((size_t)NN * 4);
  int* excl = (int*)take((size_t)NN * 4);
  int* bstart = (int*)take(NBKT * 4);
  int* gcursor = (int*)take(NBKT * 4);
  int* btot = (int*)take(NBKT * 4);
  int* bbase = (int*)take(NBKT * 4);
  int* list = (int*)take((size_t)MROWS * 4);
  int* rowmap = (int*)take((size_t)MROWS * 4);
  unsigned* ebuf = (unsigned*)take((size_t)NE * 4);
  int* csr = (int*)take(CSRN * 4);
  unsigned short* x0 = (unsigned short*)take((size_t)(NN + 1) * DD * 2);
  unsigned short* x1 = (unsigned short*)take((size_t)(NN + 1) * DD * 2);
  unsigned short* x2 = (unsigned short*)take((size_t)(NN + 1) * DD * 2);
  unsigned short* zbuf = (unsigned short*)take((size_t)MROWS * MD * 2);
  unsigned short* Wbf = (unsigned short*)take((size_t)MD * MD * 2);
  (void)ws_size; (void)in_sizes; (void)n_in; (void)out_size;

  hipMemsetAsync(zblk, 0, (size_t)(NBKT + 1 + NN) * 4, stream);
  hipMemsetAsync(uidx, 0xFF, (size_t)NN * 4, stream);  // -1

  // ---- CSR build: 2-level counting sort, streaming traffic only ----
  k_histo<<<1024, 256, 0, stream>>>(edst, bcnt);
  k_bscan<<<1, 256, 0, stream>>>(bcnt, gcursor, bstart);
  k_binA<<<(NE + TILE - 1) / TILE, 256, 0, stream>>>(esrc, edst, gcursor, ebuf);
  k_degB<<<NBKT, 256, 0, stream>>>(ebuf, bstart, bcnt, degI, dinv, excl, btot, x0, x1, x2);
  k_bscan2<<<1, 256, 0, stream>>>(btot, bbase);
  k_binB<<<NBKT, 256, 0, stream>>>(ebuf, bstart, bcnt, excl, bbase, btot, rowstart, csr);

  k_mark<<<(2 * SEL + 255) / 256, 256, 0, stream>>>(send, recv, mark);
  k_compact<<<(NN + 255) / 256, 256, 0, stream>>>(mark, list, lcnt, uidx);
  k_rowmap<<<MROWS / 256, 256, 0, stream>>>(send, recv, uidx, rowmap);
  k_conv<<<(MD * MD / 4 + 255) / 256, 256, 0, stream>>>(W, Wbf, MD * MD / 4);
  k_conv_emb2<<<(NN + 3) / 4, 256, 0, stream>>>(emb, dinv, uidx, x0, zbuf);

  // 2 full fused layers; masked final layer writes z only
  k_aggf<1><<<2048, 256, 0, stream>>>(rowstart, degI, csr, dinv, x0, x1,
                                      zbuf, uidx, 128, list, lcnt);
  k_aggf<1><<<2048, 256, 0, stream>>>(rowstart, degI, csr, dinv, x1, x2,
                                      zbuf, uidx, 256, list, lcnt);
  k_aggf<0><<<1024, 256, 0, stream>>>(rowstart, degI, csr, dinv, x2, x0,
                                      zbuf, uidx, 384, list, lcnt);

  k_gemm<<<(MROWS / 128) * (MD / 128), 256, 0, stream>>>(zbuf, rowmap, Wbf, bias, out);
}

// Round 9
// 318.875 us; speedup vs baseline: 1.2213x; 1.0081x over previous
//
#include <hip/hip_runtime.h>

#define NN 100000      // nodes
#define NE 1600000     // edges
#define DD 128         // input dim (elements per row)
#define MD 512         // mlp dim = 128*4
#define SEL 16384      // senders count
#define MROWS 32768    // senders + receivers rows
#define NBKT 196       // buckets of 512 nodes
#define TILE 4096      // edges per k_binA block
#define SEGCAP 16384   // padded CSR slots per bucket

typedef __attribute__((ext_vector_type(8))) short bf16x8;
typedef __attribute__((ext_vector_type(4))) float f32x4;

__device__ __forceinline__ unsigned short f2bf(float f) {
  unsigned u = __float_as_uint(f);
  u += 0x7fff + ((u >> 16) & 1);   // round-to-nearest-even
  return (unsigned short)(u >> 16);
}
__device__ __forceinline__ float bflo(unsigned v) { return __uint_as_float(v << 16); }
__device__ __forceinline__ float bfhi(unsigned v) { return __uint_as_float(v & 0xffff0000u); }

// ---- bucket histogram over dst (one streaming pass) ----
__global__ __launch_bounds__(256) void k_histo(const int* __restrict__ dst,
                                               int* __restrict__ bcnt) {
  __shared__ int h[NBKT];
  for (int i = threadIdx.x; i < NBKT; i += 256) h[i] = 0;
  __syncthreads();
  for (long e = blockIdx.x * 256L + threadIdx.x; e < NE; e += (long)gridDim.x * 256)
    atomicAdd(&h[dst[e] >> 9], 1);
  __syncthreads();
  for (int i = threadIdx.x; i < NBKT; i += 256)
    if (h[i]) atomicAdd(&bcnt[i], h[i]);
}

// ---- bin edges by bucket (in-block bcnt scan; gcursor starts at 0) ----
__global__ __launch_bounds__(256) void k_binA(const int* __restrict__ src,
                                              const int* __restrict__ dst,
                                              const int* __restrict__ bcnt,
                                              int* __restrict__ gcursor,
                                              unsigned* __restrict__ ebuf) {
  __shared__ int hist[NBKT];
  __shared__ int base[NBKT];
  __shared__ int cnt2[NBKT];
  __shared__ int sscan[256];
  const int tid = threadIdx.x;
  const long e0 = (long)blockIdx.x * TILE;
  for (int i = tid; i < NBKT; i += 256) { hist[i] = 0; cnt2[i] = 0; }
  // inclusive scan of bcnt -> sscan
  int v = (tid < NBKT) ? bcnt[tid] : 0;
  sscan[tid] = v;
  __syncthreads();
  for (int o = 1; o < 256; o <<= 1) {
    int t2 = (tid >= o) ? sscan[tid - o] : 0;
    __syncthreads();
    sscan[tid] += t2;
    __syncthreads();
  }
  unsigned pk[16]; int bk[16];
  #pragma unroll
  for (int k = 0; k < 16; ++k) {
    const long e = e0 + k * 256 + tid;
    bk[k] = -1;
    if (e < NE) {
      const int d = dst[e], s = src[e];
      bk[k] = d >> 9;
      pk[k] = ((unsigned)s << 9) | (unsigned)(d & 511);
      atomicAdd(&hist[bk[k]], 1);
    }
  }
  __syncthreads();
  for (int i = tid; i < NBKT; i += 256) {
    const int bst = i ? sscan[i - 1] : 0;
    base[i] = bst + atomicAdd(&gcursor[i], hist[i]);
  }
  __syncthreads();
  #pragma unroll
  for (int k = 0; k < 16; ++k) {
    if (bk[k] >= 0) {
      const int lp = atomicAdd(&cnt2[bk[k]], 1);
      ebuf[base[bk[k]] + lp] = pk[k];
    }
  }
}

// ---- per-bucket degree + dinv + local padded-offset scan + bucket totals ----
__global__ __launch_bounds__(256) void k_degB(const unsigned* __restrict__ ebuf,
                                              const int* __restrict__ bcnt,
                                              int* __restrict__ deg,
                                              float* __restrict__ dinv,
                                              int* __restrict__ excl,
                                              int* __restrict__ btot,
                                              unsigned short* __restrict__ x0,
                                              unsigned short* __restrict__ x1,
                                              unsigned short* __restrict__ x2) {
  __shared__ int ld[512];
  __shared__ int ps[256];
  __shared__ int sc[256];
  const int b = blockIdx.x;
  const int n0 = b << 9;
  const int nn = min(512, NN - n0);
  const int tid = threadIdx.x;
  for (int i = tid; i < 512; i += 256) ld[i] = 0;
  // scan bcnt for this block's ebuf start
  int v = (tid < NBKT) ? bcnt[tid] : 0;
  sc[tid] = v;
  __syncthreads();
  for (int o = 1; o < 256; o <<= 1) {
    int t2 = (tid >= o) ? sc[tid - o] : 0;
    __syncthreads();
    sc[tid] += t2;
    __syncthreads();
  }
  const int s0 = b ? sc[b - 1] : 0;
  const int c = bcnt[b];
  for (int i = tid; i < c; i += 256) atomicAdd(&ld[ebuf[s0 + i] & 511], 1);
  __syncthreads();
  const int d0 = (tid * 2 < nn) ? ld[tid * 2] : 0;
  const int d1 = (tid * 2 + 1 < nn) ? ld[tid * 2 + 1] : 0;
  const int p0 = (d0 + 7) & ~7, p1 = (d1 + 7) & ~7;
  ps[tid] = p0 + p1;
  __syncthreads();
  for (int o = 1; o < 256; o <<= 1) {
    int t2 = (tid >= o) ? ps[tid - o] : 0;
    __syncthreads();
    ps[tid] += t2;
    __syncthreads();
  }
  const int exbase = ps[tid] - (p0 + p1);
  if (tid * 2 < nn) {
    deg[n0 + tid * 2] = d0;
    dinv[n0 + tid * 2] = rsqrtf(fmaxf((float)d0, 1.f));
    excl[n0 + tid * 2] = exbase;
  }
  if (tid * 2 + 1 < nn) {
    deg[n0 + tid * 2 + 1] = d1;
    dinv[n0 + tid * 2 + 1] = rsqrtf(fmaxf((float)d1, 1.f));
    excl[n0 + tid * 2 + 1] = exbase + p0;
  }
  if (tid == 255) btot[b] = ps[255];
  if (b == 0 && tid < 64) {  // zero the sentinel row NN of each x buffer
    ((unsigned*)(x0 + (size_t)NN * DD))[tid] = 0u;
    ((unsigned*)(x1 + (size_t)NN * DD))[tid] = 0u;
    ((unsigned*)(x2 + (size_t)NN * DD))[tid] = 0u;
  }
}

// ---- per-bucket LDS scatter into padded CSR, coalesced out; pads=NN ----
__global__ __launch_bounds__(256) void k_binB(const unsigned* __restrict__ ebuf,
                                              const int* __restrict__ bcnt,
                                              const int* __restrict__ btot,
                                              const int* __restrict__ excl,
                                              int* __restrict__ rowstart,
                                              int* __restrict__ csr) {
  __shared__ int seg[SEGCAP];
  __shared__ int rs[512];
  __shared__ int cnt[512];
  __shared__ int sm[256];
  const int b = blockIdx.x;
  const int n0 = b << 9;
  const int nn = min(512, NN - n0);
  const int tid = threadIdx.x;
  // scan bcnt -> ebuf start
  int v = (tid < NBKT) ? bcnt[tid] : 0;
  sm[tid] = v;
  __syncthreads();
  for (int o = 1; o < 256; o <<= 1) {
    int t2 = (tid >= o) ? sm[tid - o] : 0;
    __syncthreads();
    sm[tid] += t2;
    __syncthreads();
  }
  const int s0 = b ? sm[b - 1] : 0;
  __syncthreads();
  // scan btot -> csr segment base
  v = (tid < NBKT) ? btot[tid] : 0;
  sm[tid] = v;
  __syncthreads();
  for (int o = 1; o < 256; o <<= 1) {
    int t2 = (tid >= o) ? sm[tid - o] : 0;
    __syncthreads();
    sm[tid] += t2;
    __syncthreads();
  }
  const int seg0 = b ? sm[b - 1] : 0;
  const int seglen = btot[b];
  for (int i = tid; i < nn; i += 256) {
    const int ex = excl[n0 + i];
    rs[i] = ex;
    cnt[i] = 0;
    rowstart[n0 + i] = seg0 + ex;
  }
  for (int i = tid; i < seglen; i += 256) seg[i] = NN;  // sentinel pad
  __syncthreads();
  const int c = bcnt[b];
  for (int i = tid; i < c; i += 256) {
    const unsigned e = ebuf[s0 + i];
    const int dl = e & 511;
    const int pos = rs[dl] + atomicAdd(&cnt[dl], 1);
    seg[pos] = (int)(e >> 9);
  }
  __syncthreads();
  for (int i = tid; i < seglen; i += 256) csr[seg0 + i] = seg[i];
}

// ---- mark + compact + unique-index the nodes needed by z-gather ----
__global__ void k_mark(const int* __restrict__ sl, const int* __restrict__ rl,
                       int* __restrict__ mark) {
  int i = blockIdx.x * blockDim.x + threadIdx.x;
  if (i < SEL) mark[sl[i]] = 1;
  else if (i < 2 * SEL) mark[rl[i - SEL]] = 1;
}

__global__ void k_compact(const int* __restrict__ mark, int* __restrict__ list,
                          int* __restrict__ cnt, int* __restrict__ uidx) {
  int n = blockIdx.x * blockDim.x + threadIdx.x;
  if (n < NN && mark[n]) {
    int p = atomicAdd(cnt, 1);
    list[p] = n;
    uidx[n] = p;
  }
}

// ---- fused aggregation (round-7 gather pattern) + z-normalize write ----
// u_next[d] = dinv[d]^2 * sum_{s in N(d)} u[s]; 4B/lane, 8 rows in flight.
template<int WX>
__global__ __launch_bounds__(256) void k_aggf(const int* __restrict__ rowstart,
                                              const int* __restrict__ deg,
                                              const int* __restrict__ csr,
                                              const float* __restrict__ dinv,
                                              const unsigned short* __restrict__ xin,
                                              unsigned short* __restrict__ xout,
                                              unsigned short* __restrict__ zbuf,
                                              const int* __restrict__ uidx,
                                              int zcol,
                                              const int* __restrict__ list,
                                              const int* __restrict__ lcnt) {
  const int lane = threadIdx.x & 63;
  const int wid = (blockIdx.x * blockDim.x + threadIdx.x) >> 6;
  const int nw = (gridDim.x * blockDim.x) >> 6;
  const int total = WX ? NN : *lcnt;
  for (int it = wid; it < total; it += nw) {
    const int n = WX ? it : list[it];
    const int start = rowstart[n];
    const int cntp = (deg[n] + 7) & ~7;
    float ax[8], ay[8];
    #pragma unroll
    for (int u = 0; u < 8; ++u) { ax[u] = 0.f; ay[u] = 0.f; }
    for (int j = 0; j < cntp; j += 8) {
      const int4 e0 = *(const int4*)(csr + start + j);
      const int4 e1 = *(const int4*)(csr + start + j + 4);
      unsigned v[8];
      v[0] = ((const unsigned*)(xin + (size_t)e0.x * DD))[lane];
      v[1] = ((const unsigned*)(xin + (size_t)e0.y * DD))[lane];
      v[2] = ((const unsigned*)(xin + (size_t)e0.z * DD))[lane];
      v[3] = ((const unsigned*)(xin + (size_t)e0.w * DD))[lane];
      v[4] = ((const unsigned*)(xin + (size_t)e1.x * DD))[lane];
      v[5] = ((const unsigned*)(xin + (size_t)e1.y * DD))[lane];
      v[6] = ((const unsigned*)(xin + (size_t)e1.z * DD))[lane];
      v[7] = ((const unsigned*)(xin + (size_t)e1.w * DD))[lane];
      #pragma unroll
      for (int u = 0; u < 8; ++u) { ax[u] += bflo(v[u]); ay[u] += bfhi(v[u]); }
    }
    const float s = dinv[n] * dinv[n];
    const float rx = (((ax[0] + ax[1]) + (ax[2] + ax[3])) + ((ax[4] + ax[5]) + (ax[6] + ax[7]))) * s;
    const float ry = (((ay[0] + ay[1]) + (ay[2] + ay[3])) + ((ay[4] + ay[5]) + (ay[6] + ay[7]))) * s;
    if (WX)
      ((unsigned*)(xout + (size_t)n * DD))[lane] = ((unsigned)f2bf(ry) << 16) | f2bf(rx);
    const int uz = uidx[n];
    if (uz >= 0) {
      float ss = fmaf(rx, rx, ry * ry);
      #pragma unroll
      for (int m = 32; m >= 1; m >>= 1) ss += __shfl_xor(ss, m);
      const float sc = 1.0f / fmaxf(sqrtf(ss), 1e-12f);
      *(unsigned*)(zbuf + (size_t)uz * MD + zcol + lane * 2) =
          ((unsigned)f2bf(ry * sc) << 16) | f2bf(rx * sc);
    }
  }
}

// ---- W f32 -> bf16 ----
__global__ void k_conv(const float* __restrict__ in, unsigned short* __restrict__ out,
                       int n4) {
  int i = blockIdx.x * blockDim.x + threadIdx.x;
  if (i >= n4) return;
  float4 v = ((const float4*)in)[i];
  ushort4 o;
  o.x = f2bf(v.x); o.y = f2bf(v.y); o.z = f2bf(v.z); o.w = f2bf(v.w);
  ((ushort4*)out)[i] = o;
}

// ---- emb f32 -> u0 bf16 = dinv*emb, fused z0 = normalize(emb) for marked ----
__global__ __launch_bounds__(256) void k_conv_emb2(const float* __restrict__ emb,
                                                   const float* __restrict__ dinv,
                                                   const int* __restrict__ uidx,
                                                   unsigned short* __restrict__ x0,
                                                   unsigned short* __restrict__ zbuf) {
  const int lane = threadIdx.x & 63;
  const int n = blockIdx.x * 4 + (threadIdx.x >> 6);
  if (n >= NN) return;
  const float2 v = ((const float2*)(emb + (size_t)n * DD))[lane];
  const float d = dinv[n];
  *(unsigned*)(x0 + (size_t)n * DD + lane * 2) =
      ((unsigned)f2bf(v.y * d) << 16) | f2bf(v.x * d);
  const int uz = uidx[n];
  if (uz >= 0) {
    float ss = fmaf(v.x, v.x, v.y * v.y);
    #pragma unroll
    for (int m = 32; m >= 1; m >>= 1) ss += __shfl_xor(ss, m);
    const float sc = 1.0f / fmaxf(sqrtf(ss), 1e-12f);
    *(unsigned*)(zbuf + (size_t)uz * MD + lane * 2) =
        ((unsigned)f2bf(v.y * sc) << 16) | f2bf(v.x * sc);
  }
}

// ---- MFMA GEMM, inline row lookup, XCD swizzle, LDS epilogue ----
// out[i][j] = sum_k zbuf[uidx[node(i)]][k] * W[j][k] + bias[j]
__global__ __launch_bounds__(256) void k_gemm(const unsigned short* __restrict__ zbuf,
                                              const int* __restrict__ sl,
                                              const int* __restrict__ rl,
                                              const int* __restrict__ uidx,
                                              const unsigned short* __restrict__ B,
                                              const float* __restrict__ bias,
                                              float* __restrict__ out) {
  __shared__ __align__(16) char smraw[20480];
  unsigned short (*As)[40] = (unsigned short(*)[40])smraw;            // 10240 B
  unsigned short (*Bs)[40] = (unsigned short(*)[40])(smraw + 10240);  // 10240 B
  float (*et)[132] = (float(*)[132])smraw;                            // 16896 B
  const int t = threadIdx.x;
  const int bid = blockIdx.x;
  const int xcd = bid & 7;
  const int j = bid >> 3;
  const int mt = xcd * 32 + (j >> 2);
  const int nt = j & 3;
  const int i0 = mt * 128, j0 = nt * 128;
  const int lane = t & 63, wid = t >> 6;
  const int wr = wid >> 1, wc = wid & 1;
  const int fr = lane & 15, kg = lane >> 4;
  const int srow = t >> 2, seg = t & 3;
  const int r0 = i0 + srow, r1 = r0 + 64;
  const int nd0 = (r0 < SEL) ? sl[r0] : rl[r0 - SEL];
  const int nd1 = (r1 < SEL) ? sl[r1] : rl[r1 - SEL];
  const unsigned short* pa0 = zbuf + (size_t)uidx[nd0] * MD + seg * 8;
  const unsigned short* pa1 = zbuf + (size_t)uidx[nd1] * MD + seg * 8;
  const unsigned short* pb0 = B + (size_t)(j0 + srow) * MD + seg * 8;
  const unsigned short* pb1 = B + (size_t)(j0 + srow + 64) * MD + seg * 8;
  f32x4 acc[4][4] = {};
  for (int k0 = 0; k0 < MD; k0 += 32) {
    *(float4*)(&As[srow][seg * 8]) = *(const float4*)(pa0 + k0);
    *(float4*)(&As[srow + 64][seg * 8]) = *(const float4*)(pa1 + k0);
    *(float4*)(&Bs[srow][seg * 8]) = *(const float4*)(pb0 + k0);
    *(float4*)(&Bs[srow + 64][seg * 8]) = *(const float4*)(pb1 + k0);
    __syncthreads();
    bf16x8 af[4], bfr[4];
    #pragma unroll
    for (int m = 0; m < 4; ++m)
      af[m] = *(const bf16x8*)(&As[wr * 64 + m * 16 + fr][kg * 8]);
    #pragma unroll
    for (int n = 0; n < 4; ++n)
      bfr[n] = *(const bf16x8*)(&Bs[wc * 64 + n * 16 + fr][kg * 8]);
    #pragma unroll
    for (int m = 0; m < 4; ++m)
      #pragma unroll
      for (int n = 0; n < 4; ++n)
        acc[m][n] = __builtin_amdgcn_mfma_f32_16x16x32_bf16(af[m], bfr[n], acc[m][n], 0, 0, 0);
    __syncthreads();
  }
  // epilogue: per m-chunk stage 32x128 f32 in LDS, write 512B-contiguous rows
  #pragma unroll
  for (int m = 0; m < 4; ++m) {
    __syncthreads();
    #pragma unroll
    for (int n = 0; n < 4; ++n)
      #pragma unroll
      for (int r = 0; r < 4; ++r)
        et[wr * 16 + kg * 4 + r][wc * 64 + n * 16 + fr] = acc[m][n][r];
    __syncthreads();
    #pragma unroll
    for (int w = 0; w < 4; ++w) {
      const int idx = w * 256 + t;
      const int lrow = idx >> 5, lc4 = idx & 31;
      const int grow = i0 + (lrow >> 4) * 64 + m * 16 + (lrow & 15);
      const int gcol = j0 + lc4 * 4;
      const float4 bv = *(const float4*)(bias + gcol);
      float4 o;
      o.x = et[lrow][lc4 * 4 + 0] + bv.x;
      o.y = et[lrow][lc4 * 4 + 1] + bv.y;
      o.z = et[lrow][lc4 * 4 + 2] + bv.z;
      o.w = et[lrow][lc4 * 4 + 3] + bv.w;
      *(float4*)(out + (size_t)grow * MD + gcol) = o;
    }
  }
}

extern "C" void kernel_launch(void* const* d_in, const int* in_sizes, int n_in,
                              void* d_out, int out_size, void* d_ws, size_t ws_size,
                              hipStream_t stream) {
  const float* emb = (const float*)d_in[0];
  const int* ei = (const int*)d_in[1];
  const int* esrc = ei;                     // edge_index[0]
  const int* edst = ei + NE;                // edge_index[1]
  const int* send = (const int*)d_in[2];
  const int* recv = (const int*)d_in[3];
  const float* W = (const float*)d_in[4];
  const float* bias = (const float*)d_in[5];
  float* out = (float*)d_out;

  char* ws = (char*)d_ws;
  size_t off = 0;
  auto take = [&](size_t b) {
    char* p = ws + off;
    off = (off + b + 1023) & ~(size_t)1023;
    return p;
  };
  const size_t CSRN = (size_t)NE + 8 * (size_t)NN;  // padded CSR capacity
  int* zblk = (int*)take((size_t)(2 * NBKT + 1 + NN) * 4);  // bcnt|gcursor|lcnt|mark
  int* bcnt = zblk;
  int* gcursor = zblk + NBKT;
  int* lcnt = zblk + 2 * NBKT;
  int* mark = zblk + 2 * NBKT + 1;
  int* uidx = (int*)take((size_t)NN * 4);
  float* dinv = (float*)take((size_t)NN * 4);
  int* degI = (int*)take((size_t)NN * 4);
  int* rowstart = (int*)take((size_t)NN * 4);
  int* excl = (int*)take((size_t)NN * 4);
  int* btot = (int*)take(NBKT * 4);
  int* list = (int*)take((size_t)MROWS * 4);
  unsigned* ebuf = (unsigned*)take((size_t)NE * 4);
  int* csr = (int*)take(CSRN * 4);
  unsigned short* x0 = (unsigned short*)take((size_t)(NN + 1) * DD * 2);
  unsigned short* x1 = (unsigned short*)take((size_t)(NN + 1) * DD * 2);
  unsigned short* x2 = (unsigned short*)take((size_t)(NN + 1) * DD * 2);
  unsigned short* zbuf = (unsigned short*)take((size_t)MROWS * MD * 2);
  unsigned short* Wbf = (unsigned short*)take((size_t)MD * MD * 2);
  (void)ws_size; (void)in_sizes; (void)n_in; (void)out_size;

  hipMemsetAsync(zblk, 0, (size_t)(2 * NBKT + 1 + NN) * 4, stream);
  hipMemsetAsync(uidx, 0xFF, (size_t)NN * 4, stream);  // -1

  // ---- CSR build: 2-level counting sort (scans folded into blocks) ----
  k_histo<<<1024, 256, 0, stream>>>(edst, bcnt);
  k_binA<<<(NE + TILE - 1) / TILE, 256, 0, stream>>>(esrc, edst, bcnt, gcursor, ebuf);
  k_degB<<<NBKT, 256, 0, stream>>>(ebuf, bcnt, degI, dinv, excl, btot, x0, x1, x2);
  k_binB<<<NBKT, 256, 0, stream>>>(ebuf, bcnt, btot, excl, rowstart, csr);

  k_mark<<<(2 * SEL + 255) / 256, 256, 0, stream>>>(send, recv, mark);
  k_compact<<<(NN + 255) / 256, 256, 0, stream>>>(mark, list, lcnt, uidx);
  k_conv<<<(MD * MD / 4 + 255) / 256, 256, 0, stream>>>(W, Wbf, MD * MD / 4);
  k_conv_emb2<<<(NN + 3) / 4, 256, 0, stream>>>(emb, dinv, uidx, x0, zbuf);

  // 2 full fused layers; masked final layer writes z only
  k_aggf<1><<<2048, 256, 0, stream>>>(rowstart, degI, csr, dinv, x0, x1,
                                      zbuf, uidx, 128, list, lcnt);
  k_aggf<1><<<2048, 256, 0, stream>>>(rowstart, degI, csr, dinv, x1, x2,
                                      zbuf, uidx, 256, list, lcnt);
  k_aggf<0><<<1024, 256, 0, stream>>>(rowstart, degI, csr, dinv, x2, x0,
                                      zbuf, uidx, 384, list, lcnt);

  k_gemm<<<(MROWS / 128) * (MD / 128), 256, 0, stream>>>(zbuf, send, recv, uidx,
                                                         Wbf, bias, out);
}

// Round 10
// 288.996 us; speedup vs baseline: 1.3476x; 1.1034x over previous
//
#include <hip/hip_runtime.h>

#define NN 100000      // nodes
#define NE 1600000     // edges
#define DD 128         // input dim (elements per row)
#define MD 512         // mlp dim = 128*4
#define SEL 16384      // senders count
#define MROWS 32768    // senders + receivers rows
#define NBKT 196       // buckets of 512 nodes
#define TILE 4096      // edges per k_binA block
#define SEGCAP 16384   // per-bucket ebuf/csr slot capacity (mean ~8192/9984)

typedef __attribute__((ext_vector_type(8))) short bf16x8;
typedef __attribute__((ext_vector_type(4))) float f32x4;

__device__ __forceinline__ unsigned short f2bf(float f) {
  unsigned u = __float_as_uint(f);
  u += 0x7fff + ((u >> 16) & 1);   // round-to-nearest-even
  return (unsigned short)(u >> 16);
}
__device__ __forceinline__ float bflo(unsigned v) { return __uint_as_float(v << 16); }
__device__ __forceinline__ float bfhi(unsigned v) { return __uint_as_float(v & 0xffff0000u); }

// ---- bin edges by bucket into strided ebuf slices (no pre-histogram) ----
// ebuf[b*SEGCAP + slot] = src<<9 | (dst&511); gcursor[b] ends as bucket count.
__global__ __launch_bounds__(256) void k_binA(const int* __restrict__ src,
                                              const int* __restrict__ dst,
                                              int* __restrict__ gcursor,
                                              unsigned* __restrict__ ebuf) {
  __shared__ int hist[NBKT];
  __shared__ int base[NBKT];
  __shared__ int cnt2[NBKT];
  const int tid = threadIdx.x;
  const long e0 = (long)blockIdx.x * TILE;
  for (int i = tid; i < NBKT; i += 256) { hist[i] = 0; cnt2[i] = 0; }
  __syncthreads();
  unsigned pk[16]; int bk[16];
  #pragma unroll
  for (int k = 0; k < 16; ++k) {
    const long e = e0 + k * 256 + tid;
    bk[k] = -1;
    if (e < NE) {
      const int d = dst[e], s = src[e];
      bk[k] = d >> 9;
      pk[k] = ((unsigned)s << 9) | (unsigned)(d & 511);
      atomicAdd(&hist[bk[k]], 1);
    }
  }
  __syncthreads();
  for (int i = tid; i < NBKT; i += 256)
    base[i] = i * SEGCAP + atomicAdd(&gcursor[i], hist[i]);
  __syncthreads();
  #pragma unroll
  for (int k = 0; k < 16; ++k) {
    if (bk[k] >= 0) {
      const int lp = atomicAdd(&cnt2[bk[k]], 1);
      ebuf[base[bk[k]] + lp] = pk[k];
    }
  }
}

// ---- per-bucket degree + dinv + local padded-offset scan + bucket totals ----
__global__ __launch_bounds__(256) void k_degB(const unsigned* __restrict__ ebuf,
                                              const int* __restrict__ bcnt,
                                              int* __restrict__ deg,
                                              float* __restrict__ dinv,
                                              int* __restrict__ excl,
                                              int* __restrict__ btot,
                                              unsigned short* __restrict__ x0,
                                              unsigned short* __restrict__ x1,
                                              unsigned short* __restrict__ x2) {
  __shared__ int ld[512];
  __shared__ int ps[256];
  const int b = blockIdx.x;
  const int n0 = b << 9;
  const int nn = min(512, NN - n0);
  const int tid = threadIdx.x;
  for (int i = tid; i < 512; i += 256) ld[i] = 0;
  __syncthreads();
  const int s0 = b * SEGCAP;
  const int c = bcnt[b];
  for (int i = tid; i < c; i += 256) atomicAdd(&ld[ebuf[s0 + i] & 511], 1);
  __syncthreads();
  const int d0 = (tid * 2 < nn) ? ld[tid * 2] : 0;
  const int d1 = (tid * 2 + 1 < nn) ? ld[tid * 2 + 1] : 0;
  const int p0 = (d0 + 7) & ~7, p1 = (d1 + 7) & ~7;
  ps[tid] = p0 + p1;
  __syncthreads();
  for (int o = 1; o < 256; o <<= 1) {
    int t2 = (tid >= o) ? ps[tid - o] : 0;
    __syncthreads();
    ps[tid] += t2;
    __syncthreads();
  }
  const int exbase = ps[tid] - (p0 + p1);
  if (tid * 2 < nn) {
    deg[n0 + tid * 2] = d0;
    dinv[n0 + tid * 2] = rsqrtf(fmaxf((float)d0, 1.f));
    excl[n0 + tid * 2] = exbase;
  }
  if (tid * 2 + 1 < nn) {
    deg[n0 + tid * 2 + 1] = d1;
    dinv[n0 + tid * 2 + 1] = rsqrtf(fmaxf((float)d1, 1.f));
    excl[n0 + tid * 2 + 1] = exbase + p0;
  }
  if (tid == 255) btot[b] = ps[255];
  if (b == 0 && tid < 64) {  // zero the sentinel row NN of each x buffer
    ((unsigned*)(x0 + (size_t)NN * DD))[tid] = 0u;
    ((unsigned*)(x1 + (size_t)NN * DD))[tid] = 0u;
    ((unsigned*)(x2 + (size_t)NN * DD))[tid] = 0u;
  }
}

// ---- per-bucket LDS scatter into padded CSR, coalesced out; pads=NN ----
__global__ __launch_bounds__(256) void k_binB(const unsigned* __restrict__ ebuf,
                                              const int* __restrict__ bcnt,
                                              const int* __restrict__ btot,
                                              const int* __restrict__ excl,
                                              int* __restrict__ rowstart,
                                              int* __restrict__ csr) {
  __shared__ int seg[SEGCAP];
  __shared__ int rs[512];
  __shared__ int cnt[512];
  __shared__ int sm[256];
  const int b = blockIdx.x;
  const int n0 = b << 9;
  const int nn = min(512, NN - n0);
  const int tid = threadIdx.x;
  // scan btot -> csr segment base
  int v = (tid < NBKT) ? btot[tid] : 0;
  sm[tid] = v;
  __syncthreads();
  for (int o = 1; o < 256; o <<= 1) {
    int t2 = (tid >= o) ? sm[tid - o] : 0;
    __syncthreads();
    sm[tid] += t2;
    __syncthreads();
  }
  const int seg0 = b ? sm[b - 1] : 0;
  const int seglen = btot[b];
  for (int i = tid; i < nn; i += 256) {
    const int ex = excl[n0 + i];
    rs[i] = ex;
    cnt[i] = 0;
    rowstart[n0 + i] = seg0 + ex;
  }
  for (int i = tid; i < seglen; i += 256) seg[i] = NN;  // sentinel pad
  __syncthreads();
  const int s0 = b * SEGCAP;
  const int c = bcnt[b];
  for (int i = tid; i < c; i += 256) {
    const unsigned e = ebuf[s0 + i];
    const int dl = e & 511;
    const int pos = rs[dl] + atomicAdd(&cnt[dl], 1);
    seg[pos] = (int)(e >> 9);
  }
  __syncthreads();
  for (int i = tid; i < seglen; i += 256) csr[seg0 + i] = seg[i];
}

// ---- mark + compact + unique-index the nodes needed by z-gather ----
__global__ void k_mark(const int* __restrict__ sl, const int* __restrict__ rl,
                       int* __restrict__ mark) {
  int i = blockIdx.x * blockDim.x + threadIdx.x;
  if (i < SEL) mark[sl[i]] = 1;
  else if (i < 2 * SEL) mark[rl[i - SEL]] = 1;
}

__global__ void k_compact(const int* __restrict__ mark, int* __restrict__ list,
                          int* __restrict__ cnt, int* __restrict__ uidx) {
  int n = blockIdx.x * blockDim.x + threadIdx.x;
  if (n < NN && mark[n]) {
    int p = atomicAdd(cnt, 1);
    list[p] = n;
    uidx[n] = p;
  }
}

// ---- fused aggregation + z-normalize write (4B/lane, 8 rows in flight) ----
// u_next[d] = dinv[d]^2 * sum_{s in N(d)} u[s]; pad slots hit zeroed row NN.
template<int WX>
__global__ __launch_bounds__(256) void k_aggf(const int* __restrict__ rowstart,
                                              const int* __restrict__ deg,
                                              const int* __restrict__ csr,
                                              const float* __restrict__ dinv,
                                              const unsigned short* __restrict__ xin,
                                              unsigned short* __restrict__ xout,
                                              unsigned short* __restrict__ zbuf,
                                              const int* __restrict__ uidx,
                                              int zcol,
                                              const int* __restrict__ list,
                                              const int* __restrict__ lcnt) {
  const int lane = threadIdx.x & 63;
  const int wid = (blockIdx.x * blockDim.x + threadIdx.x) >> 6;
  const int nw = (gridDim.x * blockDim.x) >> 6;
  const int total = WX ? NN : *lcnt;
  for (int it = wid; it < total; it += nw) {
    const int n = WX ? it : list[it];
    const int start = rowstart[n];
    const int cntp = (deg[n] + 7) & ~7;
    float ax[8], ay[8];
    #pragma unroll
    for (int u = 0; u < 8; ++u) { ax[u] = 0.f; ay[u] = 0.f; }
    for (int j = 0; j < cntp; j += 8) {
      const int4 e0 = *(const int4*)(csr + start + j);
      const int4 e1 = *(const int4*)(csr + start + j + 4);
      unsigned v[8];
      v[0] = ((const unsigned*)(xin + (size_t)e0.x * DD))[lane];
      v[1] = ((const unsigned*)(xin + (size_t)e0.y * DD))[lane];
      v[2] = ((const unsigned*)(xin + (size_t)e0.z * DD))[lane];
      v[3] = ((const unsigned*)(xin + (size_t)e0.w * DD))[lane];
      v[4] = ((const unsigned*)(xin + (size_t)e1.x * DD))[lane];
      v[5] = ((const unsigned*)(xin + (size_t)e1.y * DD))[lane];
      v[6] = ((const unsigned*)(xin + (size_t)e1.z * DD))[lane];
      v[7] = ((const unsigned*)(xin + (size_t)e1.w * DD))[lane];
      #pragma unroll
      for (int u = 0; u < 8; ++u) { ax[u] += bflo(v[u]); ay[u] += bfhi(v[u]); }
    }
    const float s = dinv[n] * dinv[n];
    const float rx = (((ax[0] + ax[1]) + (ax[2] + ax[3])) + ((ax[4] + ax[5]) + (ax[6] + ax[7]))) * s;
    const float ry = (((ay[0] + ay[1]) + (ay[2] + ay[3])) + ((ay[4] + ay[5]) + (ay[6] + ay[7]))) * s;
    if (WX)
      ((unsigned*)(xout + (size_t)n * DD))[lane] = ((unsigned)f2bf(ry) << 16) | f2bf(rx);
    const int uz = uidx[n];
    if (uz >= 0) {
      float ss = fmaf(rx, rx, ry * ry);
      #pragma unroll
      for (int m = 32; m >= 1; m >>= 1) ss += __shfl_xor(ss, m);
      const float sc = 1.0f / fmaxf(sqrtf(ss), 1e-12f);
      *(unsigned*)(zbuf + (size_t)uz * MD + zcol + lane * 2) =
          ((unsigned)f2bf(ry * sc) << 16) | f2bf(rx * sc);
    }
  }
}

// ---- emb f32 -> u0 bf16 = dinv*emb + fused z0 write; tail blocks convert W ----
__global__ __launch_bounds__(256) void k_conv_emb2(const float* __restrict__ emb,
                                                   const float* __restrict__ dinv,
                                                   const int* __restrict__ uidx,
                                                   unsigned short* __restrict__ x0,
                                                   unsigned short* __restrict__ zbuf,
                                                   const float* __restrict__ W,
                                                   unsigned short* __restrict__ Wbf) {
  if (blockIdx.x >= NN / 4) {  // W-conversion tail: 256 blocks x 256 float4
    const int i = (blockIdx.x - NN / 4) * 256 + threadIdx.x;
    if (i < MD * MD / 4) {
      float4 v = ((const float4*)W)[i];
      ushort4 o;
      o.x = f2bf(v.x); o.y = f2bf(v.y); o.z = f2bf(v.z); o.w = f2bf(v.w);
      ((ushort4*)Wbf)[i] = o;
    }
    return;
  }
  const int lane = threadIdx.x & 63;
  const int n = blockIdx.x * 4 + (threadIdx.x >> 6);
  const float2 v = ((const float2*)(emb + (size_t)n * DD))[lane];
  const float d = dinv[n];
  *(unsigned*)(x0 + (size_t)n * DD + lane * 2) =
      ((unsigned)f2bf(v.y * d) << 16) | f2bf(v.x * d);
  const int uz = uidx[n];
  if (uz >= 0) {
    float ss = fmaf(v.x, v.x, v.y * v.y);
    #pragma unroll
    for (int m = 32; m >= 1; m >>= 1) ss += __shfl_xor(ss, m);
    const float sc = 1.0f / fmaxf(sqrtf(ss), 1e-12f);
    *(unsigned*)(zbuf + (size_t)uz * MD + lane * 2) =
        ((unsigned)f2bf(v.y * sc) << 16) | f2bf(v.x * sc);
  }
}

// ---- MFMA GEMM, inline row lookup, XCD swizzle, LDS epilogue ----
// out[i][j] = sum_k zbuf[uidx[node(i)]][k] * W[j][k] + bias[j]
__global__ __launch_bounds__(256) void k_gemm(const unsigned short* __restrict__ zbuf,
                                              const int* __restrict__ sl,
                                              const int* __restrict__ rl,
                                              const int* __restrict__ uidx,
                                              const unsigned short* __restrict__ B,
                                              const float* __restrict__ bias,
                                              float* __restrict__ out) {
  __shared__ __align__(16) char smraw[20480];
  unsigned short (*As)[40] = (unsigned short(*)[40])smraw;            // 10240 B
  unsigned short (*Bs)[40] = (unsigned short(*)[40])(smraw + 10240);  // 10240 B
  float (*et)[132] = (float(*)[132])smraw;                            // 16896 B
  const int t = threadIdx.x;
  const int bid = blockIdx.x;
  const int xcd = bid & 7;
  const int j = bid >> 3;
  const int mt = xcd * 32 + (j >> 2);
  const int nt = j & 3;
  const int i0 = mt * 128, j0 = nt * 128;
  const int lane = t & 63, wid = t >> 6;
  const int wr = wid >> 1, wc = wid & 1;
  const int fr = lane & 15, kg = lane >> 4;
  const int srow = t >> 2, seg = t & 3;
  const int r0 = i0 + srow, r1 = r0 + 64;
  const int nd0 = (r0 < SEL) ? sl[r0] : rl[r0 - SEL];
  const int nd1 = (r1 < SEL) ? sl[r1] : rl[r1 - SEL];
  const unsigned short* pa0 = zbuf + (size_t)uidx[nd0] * MD + seg * 8;
  const unsigned short* pa1 = zbuf + (size_t)uidx[nd1] * MD + seg * 8;
  const unsigned short* pb0 = B + (size_t)(j0 + srow) * MD + seg * 8;
  const unsigned short* pb1 = B + (size_t)(j0 + srow + 64) * MD + seg * 8;
  f32x4 acc[4][4] = {};
  for (int k0 = 0; k0 < MD; k0 += 32) {
    *(float4*)(&As[srow][seg * 8]) = *(const float4*)(pa0 + k0);
    *(float4*)(&As[srow + 64][seg * 8]) = *(const float4*)(pa1 + k0);
    *(float4*)(&Bs[srow][seg * 8]) = *(const float4*)(pb0 + k0);
    *(float4*)(&Bs[srow + 64][seg * 8]) = *(const float4*)(pb1 + k0);
    __syncthreads();
    bf16x8 af[4], bfr[4];
    #pragma unroll
    for (int m = 0; m < 4; ++m)
      af[m] = *(const bf16x8*)(&As[wr * 64 + m * 16 + fr][kg * 8]);
    #pragma unroll
    for (int n = 0; n < 4; ++n)
      bfr[n] = *(const bf16x8*)(&Bs[wc * 64 + n * 16 + fr][kg * 8]);
    #pragma unroll
    for (int m = 0; m < 4; ++m)
      #pragma unroll
      for (int n = 0; n < 4; ++n)
        acc[m][n] = __builtin_amdgcn_mfma_f32_16x16x32_bf16(af[m], bfr[n], acc[m][n], 0, 0, 0);
    __syncthreads();
  }
  // epilogue: per m-chunk stage 32x128 f32 in LDS, write 512B-contiguous rows
  #pragma unroll
  for (int m = 0; m < 4; ++m) {
    __syncthreads();
    #pragma unroll
    for (int n = 0; n < 4; ++n)
      #pragma unroll
      for (int r = 0; r < 4; ++r)
        et[wr * 16 + kg * 4 + r][wc * 64 + n * 16 + fr] = acc[m][n][r];
    __syncthreads();
    #pragma unroll
    for (int w = 0; w < 4; ++w) {
      const int idx = w * 256 + t;
      const int lrow = idx >> 5, lc4 = idx & 31;
      const int grow = i0 + (lrow >> 4) * 64 + m * 16 + (lrow & 15);
      const int gcol = j0 + lc4 * 4;
      const float4 bv = *(const float4*)(bias + gcol);
      float4 o;
      o.x = et[lrow][lc4 * 4 + 0] + bv.x;
      o.y = et[lrow][lc4 * 4 + 1] + bv.y;
      o.z = et[lrow][lc4 * 4 + 2] + bv.z;
      o.w = et[lrow][lc4 * 4 + 3] + bv.w;
      *(float4*)(out + (size_t)grow * MD + gcol) = o;
    }
  }
}

extern "C" void kernel_launch(void* const* d_in, const int* in_sizes, int n_in,
                              void* d_out, int out_size, void* d_ws, size_t ws_size,
                              hipStream_t stream) {
  const float* emb = (const float*)d_in[0];
  const int* ei = (const int*)d_in[1];
  const int* esrc = ei;                     // edge_index[0]
  const int* edst = ei + NE;                // edge_index[1]
  const int* send = (const int*)d_in[2];
  const int* recv = (const int*)d_in[3];
  const float* W = (const float*)d_in[4];
  const float* bias = (const float*)d_in[5];
  float* out = (float*)d_out;

  char* ws = (char*)d_ws;
  size_t off = 0;
  auto take = [&](size_t b) {
    char* p = ws + off;
    off = (off + b + 1023) & ~(size_t)1023;
    return p;
  };
  const size_t CSRN = (size_t)NE + 8 * (size_t)NN;  // padded CSR capacity
  int* zblk = (int*)take((size_t)(NBKT + 1 + NN) * 4);  // gcursor|lcnt|mark
  int* gcursor = zblk;                                  // becomes bcnt
  int* lcnt = zblk + NBKT;
  int* mark = zblk + NBKT + 1;
  int* uidx = (int*)take((size_t)NN * 4);
  float* dinv = (float*)take((size_t)NN * 4);
  int* degI = (int*)take((size_t)NN * 4);
  int* rowstart = (int*)take((size_t)NN * 4);
  int* excl = (int*)take((size_t)NN * 4);
  int* btot = (int*)take(NBKT * 4);
  int* list = (int*)take((size_t)MROWS * 4);
  unsigned* ebuf = (unsigned*)take((size_t)NBKT * SEGCAP * 4);
  int* csr = (int*)take(CSRN * 4);
  unsigned short* x0 = (unsigned short*)take((size_t)(NN + 1) * DD * 2);
  unsigned short* x1 = (unsigned short*)take((size_t)(NN + 1) * DD * 2);
  unsigned short* x2 = (unsigned short*)take((size_t)(NN + 1) * DD * 2);
  unsigned short* zbuf = (unsigned short*)take((size_t)MROWS * MD * 2);
  unsigned short* Wbf = (unsigned short*)take((size_t)MD * MD * 2);
  (void)ws_size; (void)in_sizes; (void)n_in; (void)out_size;

  hipMemsetAsync(zblk, 0, (size_t)(NBKT + 1 + NN) * 4, stream);
  hipMemsetAsync(uidx, 0xFF, (size_t)NN * 4, stream);  // -1

  // ---- CSR build: single-pass bin into strided slices, then local scatter ----
  k_binA<<<(NE + TILE - 1) / TILE, 256, 0, stream>>>(esrc, edst, gcursor, ebuf);
  k_degB<<<NBKT, 256, 0, stream>>>(ebuf, gcursor, degI, dinv, excl, btot, x0, x1, x2);
  k_binB<<<NBKT, 256, 0, stream>>>(ebuf, gcursor, btot, excl, rowstart, csr);

  k_mark<<<(2 * SEL + 255) / 256, 256, 0, stream>>>(send, recv, mark);
  k_compact<<<(NN + 255) / 256, 256, 0, stream>>>(mark, list, lcnt, uidx);
  k_conv_emb2<<<NN / 4 + MD * MD / 4 / 256, 256, 0, stream>>>(emb, dinv, uidx, x0,
                                                              zbuf, W, Wbf);

  // 2 full fused layers; masked final layer writes z only
  k_aggf<1><<<2048, 256, 0, stream>>>(rowstart, degI, csr, dinv, x0, x1,
                                      zbuf, uidx, 128, list, lcnt);
  k_aggf<1><<<2048, 256, 0, stream>>>(rowstart, degI, csr, dinv, x1, x2,
                                      zbuf, uidx, 256, list, lcnt);
  k_aggf<0><<<1024, 256, 0, stream>>>(rowstart, degI, csr, dinv, x2, x0,
                                      zbuf, uidx, 384, list, lcnt);

  k_gemm<<<(MROWS / 128) * (MD / 128), 256, 0, stream>>>(zbuf, send, recv, uidx,
                                                         Wbf, bias, out);
}

// Round 11
// 287.875 us; speedup vs baseline: 1.3529x; 1.0039x over previous
//
#include <hip/hip_runtime.h>

#define NN 100000      // nodes
#define NE 1600000     // edges
#define DD 128         // input dim (elements per row)
#define MD 512         // mlp dim = 128*4
#define SEL 16384      // senders count
#define MROWS 32768    // senders + receivers rows
#define NBKT 196       // buckets of 512 nodes
#define TILE 4096      // edges per k_binA block
#define SEGCAP 16384   // per-bucket ebuf/csr slot capacity

typedef __attribute__((ext_vector_type(8))) short bf16x8;
typedef __attribute__((ext_vector_type(4))) float f32x4;

__device__ __forceinline__ unsigned short f2bf(float f) {
  unsigned u = __float_as_uint(f);
  u += 0x7fff + ((u >> 16) & 1);   // round-to-nearest-even
  return (unsigned short)(u >> 16);
}
__device__ __forceinline__ float bflo(unsigned v) { return __uint_as_float(v << 16); }
__device__ __forceinline__ float bfhi(unsigned v) { return __uint_as_float(v & 0xffff0000u); }

// ---- bin edges by bucket into strided ebuf slices (no pre-histogram) ----
__global__ __launch_bounds__(256) void k_binA(const int* __restrict__ src,
                                              const int* __restrict__ dst,
                                              int* __restrict__ gcursor,
                                              unsigned* __restrict__ ebuf) {
  __shared__ int hist[NBKT];
  __shared__ int base[NBKT];
  __shared__ int cnt2[NBKT];
  const int tid = threadIdx.x;
  const long e0 = (long)blockIdx.x * TILE;
  for (int i = tid; i < NBKT; i += 256) { hist[i] = 0; cnt2[i] = 0; }
  __syncthreads();
  unsigned pk[16]; int bk[16];
  #pragma unroll
  for (int k = 0; k < 16; ++k) {
    const long e = e0 + k * 256 + tid;
    bk[k] = -1;
    if (e < NE) {
      const int d = dst[e], s = src[e];
      bk[k] = d >> 9;
      pk[k] = ((unsigned)s << 9) | (unsigned)(d & 511);
      atomicAdd(&hist[bk[k]], 1);
    }
  }
  __syncthreads();
  for (int i = tid; i < NBKT; i += 256)
    base[i] = i * SEGCAP + atomicAdd(&gcursor[i], hist[i]);
  __syncthreads();
  #pragma unroll
  for (int k = 0; k < 16; ++k) {
    if (bk[k] >= 0) {
      const int lp = atomicAdd(&cnt2[bk[k]], 1);
      ebuf[base[bk[k]] + lp] = pk[k];
    }
  }
}

// ---- per-bucket degree + dinv + local padded-offset scan + bucket totals ----
__global__ __launch_bounds__(256) void k_degB(const unsigned* __restrict__ ebuf,
                                              const int* __restrict__ bcnt,
                                              int* __restrict__ deg,
                                              float* __restrict__ dinv,
                                              int* __restrict__ excl,
                                              int* __restrict__ btot,
                                              unsigned short* __restrict__ x0,
                                              unsigned short* __restrict__ x1,
                                              unsigned short* __restrict__ x2) {
  __shared__ int ld[512];
  __shared__ int ps[256];
  const int b = blockIdx.x;
  const int n0 = b << 9;
  const int nn = min(512, NN - n0);
  const int tid = threadIdx.x;
  for (int i = tid; i < 512; i += 256) ld[i] = 0;
  __syncthreads();
  const int s0 = b * SEGCAP;
  const int c = bcnt[b];
  for (int i = tid; i < c; i += 256) atomicAdd(&ld[ebuf[s0 + i] & 511], 1);
  __syncthreads();
  const int d0 = (tid * 2 < nn) ? ld[tid * 2] : 0;
  const int d1 = (tid * 2 + 1 < nn) ? ld[tid * 2 + 1] : 0;
  const int p0 = (d0 + 7) & ~7, p1 = (d1 + 7) & ~7;
  ps[tid] = p0 + p1;
  __syncthreads();
  for (int o = 1; o < 256; o <<= 1) {
    int t2 = (tid >= o) ? ps[tid - o] : 0;
    __syncthreads();
    ps[tid] += t2;
    __syncthreads();
  }
  const int exbase = ps[tid] - (p0 + p1);
  if (tid * 2 < nn) {
    deg[n0 + tid * 2] = d0;
    dinv[n0 + tid * 2] = rsqrtf(fmaxf((float)d0, 1.f));
    excl[n0 + tid * 2] = exbase;
  }
  if (tid * 2 + 1 < nn) {
    deg[n0 + tid * 2 + 1] = d1;
    dinv[n0 + tid * 2 + 1] = rsqrtf(fmaxf((float)d1, 1.f));
    excl[n0 + tid * 2 + 1] = exbase + p0;
  }
  if (tid == 255) btot[b] = ps[255];
  if (b == 0 && tid < 64) {  // zero the sentinel row NN of each x buffer
    ((unsigned*)(x0 + (size_t)NN * DD))[tid] = 0u;
    ((unsigned*)(x1 + (size_t)NN * DD))[tid] = 0u;
    ((unsigned*)(x2 + (size_t)NN * DD))[tid] = 0u;
  }
}

// ---- per-bucket LDS scatter into padded CSR, coalesced out; pads=NN ----
__global__ __launch_bounds__(256) void k_binB(const unsigned* __restrict__ ebuf,
                                              const int* __restrict__ bcnt,
                                              const int* __restrict__ btot,
                                              const int* __restrict__ excl,
                                              int* __restrict__ rowstart,
                                              int* __restrict__ csr) {
  __shared__ int seg[SEGCAP];
  __shared__ int rs[512];
  __shared__ int cnt[512];
  __shared__ int sm[256];
  const int b = blockIdx.x;
  const int n0 = b << 9;
  const int nn = min(512, NN - n0);
  const int tid = threadIdx.x;
  // scan btot -> csr segment base
  int v = (tid < NBKT) ? btot[tid] : 0;
  sm[tid] = v;
  __syncthreads();
  for (int o = 1; o < 256; o <<= 1) {
    int t2 = (tid >= o) ? sm[tid - o] : 0;
    __syncthreads();
    sm[tid] += t2;
    __syncthreads();
  }
  const int seg0 = b ? sm[b - 1] : 0;
  const int seglen = btot[b];
  for (int i = tid; i < nn; i += 256) {
    const int ex = excl[n0 + i];
    rs[i] = ex;
    cnt[i] = 0;
    rowstart[n0 + i] = seg0 + ex;
  }
  for (int i = tid; i < seglen; i += 256) seg[i] = NN;  // sentinel pad
  __syncthreads();
  const int s0 = b * SEGCAP;
  const int c = bcnt[b];
  for (int i = tid; i < c; i += 256) {
    const unsigned e = ebuf[s0 + i];
    const int dl = e & 511;
    const int pos = rs[dl] + atomicAdd(&cnt[dl], 1);
    seg[pos] = (int)(e >> 9);
  }
  __syncthreads();
  for (int i = tid; i < seglen; i += 256) csr[seg0 + i] = seg[i];
}

// ---- mark + compact + unique-index the nodes needed by z-gather ----
__global__ void k_mark(const int* __restrict__ sl, const int* __restrict__ rl,
                       int* __restrict__ mark) {
  int i = blockIdx.x * blockDim.x + threadIdx.x;
  if (i < SEL) mark[sl[i]] = 1;
  else if (i < 2 * SEL) mark[rl[i - SEL]] = 1;
}

__global__ void k_compact(const int* __restrict__ mark, int* __restrict__ list,
                          int* __restrict__ cnt, int* __restrict__ uidx) {
  int n = blockIdx.x * blockDim.x + threadIdx.x;
  if (n < NN && mark[n]) {
    int p = atomicAdd(cnt, 1);
    list[p] = n;
    uidx[n] = p;  // note: uidx[list[i]] == i
  }
}

// ---- feature-split aggregation: wave = 2 (node,half) items ----
// Half h is processed only by blocks with (bid&7)>>2 == h so each XCD group's
// gather working set is one 12.8 MB half of x (XCD-affinity heuristic; perf
// only). u_next[d] = dinv[d]^2 * sum_{s in N(d)} u[s]. 8 gathers in flight,
// pad slots hit zeroed sentinel row NN. WX=1: xout row = n; WX=0: compact
// output row = idx (== uidx[n]) into u3c.
template<int WX>
__global__ __launch_bounds__(256) void k_aggs(const int* __restrict__ rowstart,
                                              const int* __restrict__ deg,
                                              const int* __restrict__ csr,
                                              const float* __restrict__ dinv,
                                              const unsigned short* __restrict__ xin,
                                              unsigned short* __restrict__ xout,
                                              const int* __restrict__ list,
                                              const int* __restrict__ lcnt) {
  const int lane = threadIdx.x & 63;
  const int hi = lane >> 5, l5 = lane & 31;
  const int bid = blockIdx.x;
  const int xcd = bid & 7;
  const int h = xcd >> 2;                       // feature half
  const int g = (bid >> 3) * 4 + (xcd & 3);     // block index within half-group
  const int wvh = g * 4 + (threadIdx.x >> 6);   // wave index within half-group
  const int stride = gridDim.x * 2;             // waves per half-group
  const int xoff = h * 64;                      // element offset of this half
  const int total = WX ? NN : *lcnt;
  for (int p = wvh; 2 * p < total; p += stride) {
    const int idx = 2 * p + hi;
    const bool act = idx < total;
    const int n = act ? (WX ? idx : list[idx]) : 0;
    const int start = rowstart[n];
    const int cntp = act ? ((deg[n] + 7) & ~7) : 0;
    float ax[8], ay[8];
    #pragma unroll
    for (int u = 0; u < 8; ++u) { ax[u] = 0.f; ay[u] = 0.f; }
    for (int j = 0; j < cntp; j += 8) {
      const int4 e0 = *(const int4*)(csr + start + j);
      const int4 e1 = *(const int4*)(csr + start + j + 4);
      unsigned v[8];
      v[0] = ((const unsigned*)(xin + (size_t)e0.x * DD + xoff))[l5];
      v[1] = ((const unsigned*)(xin + (size_t)e0.y * DD + xoff))[l5];
      v[2] = ((const unsigned*)(xin + (size_t)e0.z * DD + xoff))[l5];
      v[3] = ((const unsigned*)(xin + (size_t)e0.w * DD + xoff))[l5];
      v[4] = ((const unsigned*)(xin + (size_t)e1.x * DD + xoff))[l5];
      v[5] = ((const unsigned*)(xin + (size_t)e1.y * DD + xoff))[l5];
      v[6] = ((const unsigned*)(xin + (size_t)e1.z * DD + xoff))[l5];
      v[7] = ((const unsigned*)(xin + (size_t)e1.w * DD + xoff))[l5];
      #pragma unroll
      for (int u = 0; u < 8; ++u) { ax[u] += bflo(v[u]); ay[u] += bfhi(v[u]); }
    }
    if (act) {
      const float s = dinv[n] * dinv[n];
      const float rx = (((ax[0] + ax[1]) + (ax[2] + ax[3])) + ((ax[4] + ax[5]) + (ax[6] + ax[7]))) * s;
      const float ry = (((ay[0] + ay[1]) + (ay[2] + ay[3])) + ((ay[4] + ay[5]) + (ay[6] + ay[7]))) * s;
      const size_t orow = WX ? (size_t)n : (size_t)idx;
      ((unsigned*)(xout + orow * DD + xoff))[l5] =
          ((unsigned)f2bf(ry) << 16) | f2bf(rx);
    }
  }
}

// ---- all four z-slices for marked rows: z_l = normalize(u_l) ----
__global__ __launch_bounds__(256) void k_zall(const int* __restrict__ list,
                                              const int* __restrict__ lcnt,
                                              const unsigned short* __restrict__ x0,
                                              const unsigned short* __restrict__ x1,
                                              const unsigned short* __restrict__ x2,
                                              const unsigned short* __restrict__ u3c,
                                              unsigned short* __restrict__ zbuf) {
  const int lane = threadIdx.x & 63;
  const int wv = (blockIdx.x * blockDim.x + threadIdx.x) >> 6;
  const int nw = (gridDim.x * blockDim.x) >> 6;
  const int cl = *lcnt;
  for (int r = wv; r < cl; r += nw) {
    const int node = list[r];
    unsigned v[4];
    v[0] = ((const unsigned*)(x0 + (size_t)node * DD))[lane];
    v[1] = ((const unsigned*)(x1 + (size_t)node * DD))[lane];
    v[2] = ((const unsigned*)(x2 + (size_t)node * DD))[lane];
    v[3] = ((const unsigned*)(u3c + (size_t)r * DD))[lane];
    #pragma unroll
    for (int q = 0; q < 4; ++q) {
      const float a = bflo(v[q]), b = bfhi(v[q]);
      float ss = fmaf(a, a, b * b);
      #pragma unroll
      for (int m = 32; m >= 1; m >>= 1) ss += __shfl_xor(ss, m);
      const float sc = 1.0f / fmaxf(sqrtf(ss), 1e-12f);
      *(unsigned*)(zbuf + (size_t)r * MD + q * DD + lane * 2) =
          ((unsigned)f2bf(b * sc) << 16) | f2bf(a * sc);
    }
  }
}

// ---- emb f32 -> u0 bf16 = dinv*emb; tail blocks convert W ----
__global__ __launch_bounds__(256) void k_conv_emb2(const float* __restrict__ emb,
                                                   const float* __restrict__ dinv,
                                                   unsigned short* __restrict__ x0,
                                                   const float* __restrict__ W,
                                                   unsigned short* __restrict__ Wbf) {
  if (blockIdx.x >= NN / 4) {  // W-conversion tail: 256 blocks x 256 float4
    const int i = (blockIdx.x - NN / 4) * 256 + threadIdx.x;
    if (i < MD * MD / 4) {
      float4 v = ((const float4*)W)[i];
      ushort4 o;
      o.x = f2bf(v.x); o.y = f2bf(v.y); o.z = f2bf(v.z); o.w = f2bf(v.w);
      ((ushort4*)Wbf)[i] = o;
    }
    return;
  }
  const int lane = threadIdx.x & 63;
  const int n = blockIdx.x * 4 + (threadIdx.x >> 6);
  const float2 v = ((const float2*)(emb + (size_t)n * DD))[lane];
  const float d = dinv[n];
  *(unsigned*)(x0 + (size_t)n * DD + lane * 2) =
      ((unsigned)f2bf(v.y * d) << 16) | f2bf(v.x * d);
}

// ---- MFMA GEMM, inline row lookup, XCD swizzle, LDS epilogue ----
// out[i][j] = sum_k zbuf[uidx[node(i)]][k] * W[j][k] + bias[j]
__global__ __launch_bounds__(256) void k_gemm(const unsigned short* __restrict__ zbuf,
                                              const int* __restrict__ sl,
                                              const int* __restrict__ rl,
                                              const int* __restrict__ uidx,
                                              const unsigned short* __restrict__ B,
                                              const float* __restrict__ bias,
                                              float* __restrict__ out) {
  __shared__ __align__(16) char smraw[20480];
  unsigned short (*As)[40] = (unsigned short(*)[40])smraw;            // 10240 B
  unsigned short (*Bs)[40] = (unsigned short(*)[40])(smraw + 10240);  // 10240 B
  float (*et)[132] = (float(*)[132])smraw;                            // 16896 B
  const int t = threadIdx.x;
  const int bid = blockIdx.x;
  const int xcd = bid & 7;
  const int j = bid >> 3;
  const int mt = xcd * 32 + (j >> 2);
  const int nt = j & 3;
  const int i0 = mt * 128, j0 = nt * 128;
  const int lane = t & 63, wid = t >> 6;
  const int wr = wid >> 1, wc = wid & 1;
  const int fr = lane & 15, kg = lane >> 4;
  const int srow = t >> 2, seg = t & 3;
  const int r0 = i0 + srow, r1 = r0 + 64;
  const int nd0 = (r0 < SEL) ? sl[r0] : rl[r0 - SEL];
  const int nd1 = (r1 < SEL) ? sl[r1] : rl[r1 - SEL];
  const unsigned short* pa0 = zbuf + (size_t)uidx[nd0] * MD + seg * 8;
  const unsigned short* pa1 = zbuf + (size_t)uidx[nd1] * MD + seg * 8;
  const unsigned short* pb0 = B + (size_t)(j0 + srow) * MD + seg * 8;
  const unsigned short* pb1 = B + (size_t)(j0 + srow + 64) * MD + seg * 8;
  f32x4 acc[4][4] = {};
  for (int k0 = 0; k0 < MD; k0 += 32) {
    *(float4*)(&As[srow][seg * 8]) = *(const float4*)(pa0 + k0);
    *(float4*)(&As[srow + 64][seg * 8]) = *(const float4*)(pa1 + k0);
    *(float4*)(&Bs[srow][seg * 8]) = *(const float4*)(pb0 + k0);
    *(float4*)(&Bs[srow + 64][seg * 8]) = *(const float4*)(pb1 + k0);
    __syncthreads();
    bf16x8 af[4], bfr[4];
    #pragma unroll
    for (int m = 0; m < 4; ++m)
      af[m] = *(const bf16x8*)(&As[wr * 64 + m * 16 + fr][kg * 8]);
    #pragma unroll
    for (int n = 0; n < 4; ++n)
      bfr[n] = *(const bf16x8*)(&Bs[wc * 64 + n * 16 + fr][kg * 8]);
    #pragma unroll
    for (int m = 0; m < 4; ++m)
      #pragma unroll
      for (int n = 0; n < 4; ++n)
        acc[m][n] = __builtin_amdgcn_mfma_f32_16x16x32_bf16(af[m], bfr[n], acc[m][n], 0, 0, 0);
    __syncthreads();
  }
  // epilogue: per m-chunk stage 32x128 f32 in LDS, write 512B-contiguous rows
  #pragma unroll
  for (int m = 0; m < 4; ++m) {
    __syncthreads();
    #pragma unroll
    for (int n = 0; n < 4; ++n)
      #pragma unroll
      for (int r = 0; r < 4; ++r)
        et[wr * 16 + kg * 4 + r][wc * 64 + n * 16 + fr] = acc[m][n][r];
    __syncthreads();
    #pragma unroll
    for (int w = 0; w < 4; ++w) {
      const int idx = w * 256 + t;
      const int lrow = idx >> 5, lc4 = idx & 31;
      const int grow = i0 + (lrow >> 4) * 64 + m * 16 + (lrow & 15);
      const int gcol = j0 + lc4 * 4;
      const float4 bv = *(const float4*)(bias + gcol);
      float4 o;
      o.x = et[lrow][lc4 * 4 + 0] + bv.x;
      o.y = et[lrow][lc4 * 4 + 1] + bv.y;
      o.z = et[lrow][lc4 * 4 + 2] + bv.z;
      o.w = et[lrow][lc4 * 4 + 3] + bv.w;
      *(float4*)(out + (size_t)grow * MD + gcol) = o;
    }
  }
}

extern "C" void kernel_launch(void* const* d_in, const int* in_sizes, int n_in,
                              void* d_out, int out_size, void* d_ws, size_t ws_size,
                              hipStream_t stream) {
  const float* emb = (const float*)d_in[0];
  const int* ei = (const int*)d_in[1];
  const int* esrc = ei;                     // edge_index[0]
  const int* edst = ei + NE;                // edge_index[1]
  const int* send = (const int*)d_in[2];
  const int* recv = (const int*)d_in[3];
  const float* W = (const float*)d_in[4];
  const float* bias = (const float*)d_in[5];
  float* out = (float*)d_out;

  char* ws = (char*)d_ws;
  size_t off = 0;
  auto take = [&](size_t b) {
    char* p = ws + off;
    off = (off + b + 1023) & ~(size_t)1023;
    return p;
  };
  const size_t CSRN = (size_t)NE + 8 * (size_t)NN;  // padded CSR capacity
  int* zblk = (int*)take((size_t)(NBKT + 1 + NN) * 4);  // gcursor|lcnt|mark
  int* gcursor = zblk;                                  // becomes bcnt
  int* lcnt = zblk + NBKT;
  int* mark = zblk + NBKT + 1;
  int* uidx = (int*)take((size_t)NN * 4);
  float* dinv = (float*)take((size_t)NN * 4);
  int* degI = (int*)take((size_t)NN * 4);
  int* rowstart = (int*)take((size_t)NN * 4);
  int* excl = (int*)take((size_t)NN * 4);
  int* btot = (int*)take(NBKT * 4);
  int* list = (int*)take((size_t)MROWS * 4);
  unsigned* ebuf = (unsigned*)take((size_t)NBKT * SEGCAP * 4);
  int* csr = (int*)take(CSRN * 4);
  unsigned short* x0 = (unsigned short*)take((size_t)(NN + 1) * DD * 2);
  unsigned short* x1 = (unsigned short*)take((size_t)(NN + 1) * DD * 2);
  unsigned short* x2 = (unsigned short*)take((size_t)(NN + 1) * DD * 2);
  unsigned short* u3c = (unsigned short*)take((size_t)MROWS * DD * 2);
  unsigned short* zbuf = (unsigned short*)take((size_t)MROWS * MD * 2);
  unsigned short* Wbf = (unsigned short*)take((size_t)MD * MD * 2);
  (void)ws_size; (void)in_sizes; (void)n_in; (void)out_size;

  hipMemsetAsync(zblk, 0, (size_t)(NBKT + 1 + NN) * 4, stream);
  hipMemsetAsync(uidx, 0xFF, (size_t)NN * 4, stream);  // -1

  // ---- CSR build: single-pass bin into strided slices, then local scatter ----
  k_binA<<<(NE + TILE - 1) / TILE, 256, 0, stream>>>(esrc, edst, gcursor, ebuf);
  k_degB<<<NBKT, 256, 0, stream>>>(ebuf, gcursor, degI, dinv, excl, btot, x0, x1, x2);
  k_binB<<<NBKT, 256, 0, stream>>>(ebuf, gcursor, btot, excl, rowstart, csr);

  k_mark<<<(2 * SEL + 255) / 256, 256, 0, stream>>>(send, recv, mark);
  k_compact<<<(NN + 255) / 256, 256, 0, stream>>>(mark, list, lcnt, uidx);
  k_conv_emb2<<<NN / 4 + MD * MD / 4 / 256, 256, 0, stream>>>(emb, dinv, x0, W, Wbf);

  // 2 full feature-split layers; masked final layer -> compact u3c
  k_aggs<1><<<2048, 256, 0, stream>>>(rowstart, degI, csr, dinv, x0, x1, list, lcnt);
  k_aggs<1><<<2048, 256, 0, stream>>>(rowstart, degI, csr, dinv, x1, x2, list, lcnt);
  k_aggs<0><<<1024, 256, 0, stream>>>(rowstart, degI, csr, dinv, x2, u3c, list, lcnt);

  // all four z-slices, then the MLP
  k_zall<<<1024, 256, 0, stream>>>(list, lcnt, x0, x1, x2, u3c, zbuf);
  k_gemm<<<(MROWS / 128) * (MD / 128), 256, 0, stream>>>(zbuf, send, recv, uidx,
                                                         Wbf, bias, out);
}

// Round 12
// 263.349 us; speedup vs baseline: 1.4789x; 1.0931x over previous
//
#include <hip/hip_runtime.h>

#define NN 100000      // nodes
#define NE 1600000     // edges
#define DD 128         // input dim (elements per row)
#define MD 512         // mlp dim = 128*4
#define SEL 16384      // senders count
#define MROWS 32768    // senders + receivers rows
#define NBKT 196       // buckets of 512 nodes
#define TILE 4096      // edges per k_binA block
#define SEGCAP 16384   // per-bucket ebuf/csr slot capacity
#define NBINA ((NE + TILE - 1) / TILE)   // 391
#define NMARK ((2 * SEL + 255) / 256)    // 128
#define NCOMP ((NN + 255) / 256)         // 391

typedef __attribute__((ext_vector_type(8))) short bf16x8;
typedef __attribute__((ext_vector_type(4))) float f32x4;

__device__ __forceinline__ unsigned short f2bf(float f) {
  unsigned u = __float_as_uint(f);
  u += 0x7fff + ((u >> 16) & 1);   // round-to-nearest-even
  return (unsigned short)(u >> 16);
}
__device__ __forceinline__ float bflo(unsigned v) { return __uint_as_float(v << 16); }
__device__ __forceinline__ float bfhi(unsigned v) { return __uint_as_float(v & 0xffff0000u); }

// ---- bin edges into strided ebuf slices; tail blocks do the mark pass ----
__global__ __launch_bounds__(256) void k_binA_mark(const int* __restrict__ src,
                                                   const int* __restrict__ dst,
                                                   int* __restrict__ gcursor,
                                                   unsigned* __restrict__ ebuf,
                                                   const int* __restrict__ sl,
                                                   const int* __restrict__ rl,
                                                   int* __restrict__ mark) {
  if (blockIdx.x >= NBINA) {  // mark tail
    const int i = (blockIdx.x - NBINA) * 256 + threadIdx.x;
    if (i < SEL) mark[sl[i]] = 1;
    else if (i < 2 * SEL) mark[rl[i - SEL]] = 1;
    return;
  }
  __shared__ int hist[NBKT];
  __shared__ int base[NBKT];
  __shared__ int cnt2[NBKT];
  const int tid = threadIdx.x;
  const long e0 = (long)blockIdx.x * TILE;
  for (int i = tid; i < NBKT; i += 256) { hist[i] = 0; cnt2[i] = 0; }
  __syncthreads();
  unsigned pk[16]; int bk[16];
  #pragma unroll
  for (int k = 0; k < 16; ++k) {
    const long e = e0 + k * 256 + tid;
    bk[k] = -1;
    if (e < NE) {
      const int d = dst[e], s = src[e];
      bk[k] = d >> 9;
      pk[k] = ((unsigned)s << 9) | (unsigned)(d & 511);
      atomicAdd(&hist[bk[k]], 1);
    }
  }
  __syncthreads();
  for (int i = tid; i < NBKT; i += 256)
    base[i] = i * SEGCAP + atomicAdd(&gcursor[i], hist[i]);
  __syncthreads();
  #pragma unroll
  for (int k = 0; k < 16; ++k) {
    if (bk[k] >= 0) {
      const int lp = atomicAdd(&cnt2[bk[k]], 1);
      ebuf[base[bk[k]] + lp] = pk[k];
    }
  }
}

// ---- per-bucket degree + dinv + padded-offset scan; tail blocks compact ----
__global__ __launch_bounds__(256) void k_degB_compact(const unsigned* __restrict__ ebuf,
                                                      const int* __restrict__ bcnt,
                                                      int* __restrict__ deg,
                                                      float* __restrict__ dinv,
                                                      int* __restrict__ excl,
                                                      int* __restrict__ btot,
                                                      unsigned short* __restrict__ x0,
                                                      unsigned short* __restrict__ x1,
                                                      unsigned short* __restrict__ x2,
                                                      const int* __restrict__ mark,
                                                      int* __restrict__ list,
                                                      int* __restrict__ lcnt,
                                                      int* __restrict__ uidx) {
  if (blockIdx.x >= NBKT) {  // compact tail (mark completed last kernel)
    const int n = (blockIdx.x - NBKT) * 256 + threadIdx.x;
    if (n < NN && mark[n]) {
      const int p = atomicAdd(lcnt, 1);
      list[p] = n;
      uidx[n] = p;
    }
    return;
  }
  __shared__ int ld[512];
  __shared__ int ps[256];
  const int b = blockIdx.x;
  const int n0 = b << 9;
  const int nn = min(512, NN - n0);
  const int tid = threadIdx.x;
  for (int i = tid; i < 512; i += 256) ld[i] = 0;
  __syncthreads();
  const int s0 = b * SEGCAP;
  const int c = bcnt[b];
  for (int i = tid; i < c; i += 256) atomicAdd(&ld[ebuf[s0 + i] & 511], 1);
  __syncthreads();
  const int d0 = (tid * 2 < nn) ? ld[tid * 2] : 0;
  const int d1 = (tid * 2 + 1 < nn) ? ld[tid * 2 + 1] : 0;
  const int p0 = (d0 + 7) & ~7, p1 = (d1 + 7) & ~7;
  ps[tid] = p0 + p1;
  __syncthreads();
  for (int o = 1; o < 256; o <<= 1) {
    int t2 = (tid >= o) ? ps[tid - o] : 0;
    __syncthreads();
    ps[tid] += t2;
    __syncthreads();
  }
  const int exbase = ps[tid] - (p0 + p1);
  if (tid * 2 < nn) {
    deg[n0 + tid * 2] = d0;
    dinv[n0 + tid * 2] = rsqrtf(fmaxf((float)d0, 1.f));
    excl[n0 + tid * 2] = exbase;
  }
  if (tid * 2 + 1 < nn) {
    deg[n0 + tid * 2 + 1] = d1;
    dinv[n0 + tid * 2 + 1] = rsqrtf(fmaxf((float)d1, 1.f));
    excl[n0 + tid * 2 + 1] = exbase + p0;
  }
  if (tid == 255) btot[b] = ps[255];
  if (b == 0 && tid < 64) {  // zero the sentinel row NN of each x buffer
    ((unsigned*)(x0 + (size_t)NN * DD))[tid] = 0u;
    ((unsigned*)(x1 + (size_t)NN * DD))[tid] = 0u;
    ((unsigned*)(x2 + (size_t)NN * DD))[tid] = 0u;
  }
}

// ---- per-bucket LDS scatter into padded CSR, coalesced out; pads=NN ----
__global__ __launch_bounds__(256) void k_binB(const unsigned* __restrict__ ebuf,
                                              const int* __restrict__ bcnt,
                                              const int* __restrict__ btot,
                                              const int* __restrict__ excl,
                                              int* __restrict__ rowstart,
                                              int* __restrict__ csr) {
  __shared__ int seg[SEGCAP];
  __shared__ int rs[512];
  __shared__ int cnt[512];
  __shared__ int sm[256];
  const int b = blockIdx.x;
  const int n0 = b << 9;
  const int nn = min(512, NN - n0);
  const int tid = threadIdx.x;
  // scan btot -> csr segment base
  int v = (tid < NBKT) ? btot[tid] : 0;
  sm[tid] = v;
  __syncthreads();
  for (int o = 1; o < 256; o <<= 1) {
    int t2 = (tid >= o) ? sm[tid - o] : 0;
    __syncthreads();
    sm[tid] += t2;
    __syncthreads();
  }
  const int seg0 = b ? sm[b - 1] : 0;
  const int seglen = btot[b];
  for (int i = tid; i < nn; i += 256) {
    const int ex = excl[n0 + i];
    rs[i] = ex;
    cnt[i] = 0;
    rowstart[n0 + i] = seg0 + ex;
  }
  for (int i = tid; i < seglen; i += 256) seg[i] = NN;  // sentinel pad
  __syncthreads();
  const int s0 = b * SEGCAP;
  const int c = bcnt[b];
  for (int i = tid; i < c; i += 256) {
    const unsigned e = ebuf[s0 + i];
    const int dl = e & 511;
    const int pos = rs[dl] + atomicAdd(&cnt[dl], 1);
    seg[pos] = (int)(e >> 9);
  }
  __syncthreads();
  for (int i = tid; i < seglen; i += 256) csr[seg0 + i] = seg[i];
}

// ---- feature-split aggregation: wave = 2 (node,half) items ----
// Half h handled only by blocks with (bid&7)>>2 == h (XCD-affinity heuristic).
// u_next[d] = dinv[d]^2 * sum_{s in N(d)} u[s]; 8 gathers in flight.
__global__ __launch_bounds__(256) void k_aggs(const int* __restrict__ rowstart,
                                              const int* __restrict__ deg,
                                              const int* __restrict__ csr,
                                              const float* __restrict__ dinv,
                                              const unsigned short* __restrict__ xin,
                                              unsigned short* __restrict__ xout) {
  const int lane = threadIdx.x & 63;
  const int hi = lane >> 5, l5 = lane & 31;
  const int bid = blockIdx.x;
  const int xcd = bid & 7;
  const int h = xcd >> 2;                       // feature half
  const int g = (bid >> 3) * 4 + (xcd & 3);     // block index within half-group
  const int wvh = g * 4 + (threadIdx.x >> 6);   // wave index within half-group
  const int stride = gridDim.x * 2;             // waves per half-group
  const int xoff = h * 64;                      // element offset of this half
  for (int p = wvh; 2 * p < NN; p += stride) {
    const int idx = 2 * p + hi;
    const bool act = idx < NN;
    const int n = act ? idx : 0;
    const int start = rowstart[n];
    const int cntp = act ? ((deg[n] + 7) & ~7) : 0;
    float ax[8], ay[8];
    #pragma unroll
    for (int u = 0; u < 8; ++u) { ax[u] = 0.f; ay[u] = 0.f; }
    for (int j = 0; j < cntp; j += 8) {
      const int4 e0 = *(const int4*)(csr + start + j);
      const int4 e1 = *(const int4*)(csr + start + j + 4);
      unsigned v[8];
      v[0] = ((const unsigned*)(xin + (size_t)e0.x * DD + xoff))[l5];
      v[1] = ((const unsigned*)(xin + (size_t)e0.y * DD + xoff))[l5];
      v[2] = ((const unsigned*)(xin + (size_t)e0.z * DD + xoff))[l5];
      v[3] = ((const unsigned*)(xin + (size_t)e0.w * DD + xoff))[l5];
      v[4] = ((const unsigned*)(xin + (size_t)e1.x * DD + xoff))[l5];
      v[5] = ((const unsigned*)(xin + (size_t)e1.y * DD + xoff))[l5];
      v[6] = ((const unsigned*)(xin + (size_t)e1.z * DD + xoff))[l5];
      v[7] = ((const unsigned*)(xin + (size_t)e1.w * DD + xoff))[l5];
      #pragma unroll
      for (int u = 0; u < 8; ++u) { ax[u] += bflo(v[u]); ay[u] += bfhi(v[u]); }
    }
    if (act) {
      const float s = dinv[n] * dinv[n];
      const float rx = (((ax[0] + ax[1]) + (ax[2] + ax[3])) + ((ax[4] + ax[5]) + (ax[6] + ax[7]))) * s;
      const float ry = (((ay[0] + ay[1]) + (ay[2] + ay[3])) + ((ay[4] + ay[5]) + (ay[6] + ay[7]))) * s;
      ((unsigned*)(xout + (size_t)n * DD + xoff))[l5] =
          ((unsigned)f2bf(ry) << 16) | f2bf(rx);
    }
  }
}

// ---- layer-3 aggregation (listed nodes, full row) + all four z-slices ----
__global__ __launch_bounds__(256) void k_agg3z(const int* __restrict__ rowstart,
                                               const int* __restrict__ deg,
                                               const int* __restrict__ csr,
                                               const float* __restrict__ dinv,
                                               const unsigned short* __restrict__ x0,
                                               const unsigned short* __restrict__ x1,
                                               const unsigned short* __restrict__ x2,
                                               unsigned short* __restrict__ zbuf,
                                               const int* __restrict__ list,
                                               const int* __restrict__ lcnt) {
  const int lane = threadIdx.x & 63;
  const int wv = (blockIdx.x * blockDim.x + threadIdx.x) >> 6;
  const int nw = (gridDim.x * blockDim.x) >> 6;
  const int cl = *lcnt;
  for (int r = wv; r < cl; r += nw) {
    const int n = list[r];
    // u3 = dinv^2 * sum x2[nbrs]  (full 128-dim row, 8 gathers in flight)
    const int start = rowstart[n];
    const int cntp = (deg[n] + 7) & ~7;
    float ax[8], ay[8];
    #pragma unroll
    for (int u = 0; u < 8; ++u) { ax[u] = 0.f; ay[u] = 0.f; }
    for (int j = 0; j < cntp; j += 8) {
      const int4 e0 = *(const int4*)(csr + start + j);
      const int4 e1 = *(const int4*)(csr + start + j + 4);
      unsigned v[8];
      v[0] = ((const unsigned*)(x2 + (size_t)e0.x * DD))[lane];
      v[1] = ((const unsigned*)(x2 + (size_t)e0.y * DD))[lane];
      v[2] = ((const unsigned*)(x2 + (size_t)e0.z * DD))[lane];
      v[3] = ((const unsigned*)(x2 + (size_t)e0.w * DD))[lane];
      v[4] = ((const unsigned*)(x2 + (size_t)e1.x * DD))[lane];
      v[5] = ((const unsigned*)(x2 + (size_t)e1.y * DD))[lane];
      v[6] = ((const unsigned*)(x2 + (size_t)e1.z * DD))[lane];
      v[7] = ((const unsigned*)(x2 + (size_t)e1.w * DD))[lane];
      #pragma unroll
      for (int u = 0; u < 8; ++u) { ax[u] += bflo(v[u]); ay[u] += bfhi(v[u]); }
    }
    const float s = dinv[n] * dinv[n];
    const float rx = (((ax[0] + ax[1]) + (ax[2] + ax[3])) + ((ax[4] + ax[5]) + (ax[6] + ax[7]))) * s;
    const float ry = (((ay[0] + ay[1]) + (ay[2] + ay[3])) + ((ay[4] + ay[5]) + (ay[6] + ay[7]))) * s;
    {  // z3
      float ss = fmaf(rx, rx, ry * ry);
      #pragma unroll
      for (int m = 32; m >= 1; m >>= 1) ss += __shfl_xor(ss, m);
      const float sc = 1.0f / fmaxf(sqrtf(ss), 1e-12f);
      *(unsigned*)(zbuf + (size_t)r * MD + 384 + lane * 2) =
          ((unsigned)f2bf(ry * sc) << 16) | f2bf(rx * sc);
    }
    // z0..z2 from u0..u2 rows
    unsigned v0 = ((const unsigned*)(x0 + (size_t)n * DD))[lane];
    unsigned v1 = ((const unsigned*)(x1 + (size_t)n * DD))[lane];
    unsigned v2 = ((const unsigned*)(x2 + (size_t)n * DD))[lane];
    unsigned vv[3] = {v0, v1, v2};
    #pragma unroll
    for (int q = 0; q < 3; ++q) {
      const float a = bflo(vv[q]), b = bfhi(vv[q]);
      float ss = fmaf(a, a, b * b);
      #pragma unroll
      for (int m = 32; m >= 1; m >>= 1) ss += __shfl_xor(ss, m);
      const float sc = 1.0f / fmaxf(sqrtf(ss), 1e-12f);
      *(unsigned*)(zbuf + (size_t)r * MD + q * DD + lane * 2) =
          ((unsigned)f2bf(b * sc) << 16) | f2bf(a * sc);
    }
  }
}

// ---- emb f32 -> u0 bf16 = dinv*emb; tail blocks convert W ----
__global__ __launch_bounds__(256) void k_conv_emb2(const float* __restrict__ emb,
                                                   const float* __restrict__ dinv,
                                                   unsigned short* __restrict__ x0,
                                                   const float* __restrict__ W,
                                                   unsigned short* __restrict__ Wbf) {
  if (blockIdx.x >= NN / 4) {  // W-conversion tail: 256 blocks x 256 float4
    const int i = (blockIdx.x - NN / 4) * 256 + threadIdx.x;
    if (i < MD * MD / 4) {
      float4 v = ((const float4*)W)[i];
      ushort4 o;
      o.x = f2bf(v.x); o.y = f2bf(v.y); o.z = f2bf(v.z); o.w = f2bf(v.w);
      ((ushort4*)Wbf)[i] = o;
    }
    return;
  }
  const int lane = threadIdx.x & 63;
  const int n = blockIdx.x * 4 + (threadIdx.x >> 6);
  const float2 v = ((const float2*)(emb + (size_t)n * DD))[lane];
  const float d = dinv[n];
  *(unsigned*)(x0 + (size_t)n * DD + lane * 2) =
      ((unsigned)f2bf(v.y * d) << 16) | f2bf(v.x * d);
}

// ---- MFMA GEMM, inline row lookup, XCD swizzle, LDS epilogue ----
// out[i][j] = sum_k zbuf[uidx[node(i)]][k] * W[j][k] + bias[j]
__global__ __launch_bounds__(256) void k_gemm(const unsigned short* __restrict__ zbuf,
                                              const int* __restrict__ sl,
                                              const int* __restrict__ rl,
                                              const int* __restrict__ uidx,
                                              const unsigned short* __restrict__ B,
                                              const float* __restrict__ bias,
                                              float* __restrict__ out) {
  __shared__ __align__(16) char smraw[20480];
  unsigned short (*As)[40] = (unsigned short(*)[40])smraw;            // 10240 B
  unsigned short (*Bs)[40] = (unsigned short(*)[40])(smraw + 10240);  // 10240 B
  float (*et)[132] = (float(*)[132])smraw;                            // 16896 B
  const int t = threadIdx.x;
  const int bid = blockIdx.x;
  const int xcd = bid & 7;
  const int j = bid >> 3;
  const int mt = xcd * 32 + (j >> 2);
  const int nt = j & 3;
  const int i0 = mt * 128, j0 = nt * 128;
  const int lane = t & 63, wid = t >> 6;
  const int wr = wid >> 1, wc = wid & 1;
  const int fr = lane & 15, kg = lane >> 4;
  const int srow = t >> 2, seg = t & 3;
  const int r0 = i0 + srow, r1 = r0 + 64;
  const int nd0 = (r0 < SEL) ? sl[r0] : rl[r0 - SEL];
  const int nd1 = (r1 < SEL) ? sl[r1] : rl[r1 - SEL];
  const unsigned short* pa0 = zbuf + (size_t)uidx[nd0] * MD + seg * 8;
  const unsigned short* pa1 = zbuf + (size_t)uidx[nd1] * MD + seg * 8;
  const unsigned short* pb0 = B + (size_t)(j0 + srow) * MD + seg * 8;
  const unsigned short* pb1 = B + (size_t)(j0 + srow + 64) * MD + seg * 8;
  f32x4 acc[4][4] = {};
  for (int k0 = 0; k0 < MD; k0 += 32) {
    *(float4*)(&As[srow][seg * 8]) = *(const float4*)(pa0 + k0);
    *(float4*)(&As[srow + 64][seg * 8]) = *(const float4*)(pa1 + k0);
    *(float4*)(&Bs[srow][seg * 8]) = *(const float4*)(pb0 + k0);
    *(float4*)(&Bs[srow + 64][seg * 8]) = *(const float4*)(pb1 + k0);
    __syncthreads();
    bf16x8 af[4], bfr[4];
    #pragma unroll
    for (int m = 0; m < 4; ++m)
      af[m] = *(const bf16x8*)(&As[wr * 64 + m * 16 + fr][kg * 8]);
    #pragma unroll
    for (int n = 0; n < 4; ++n)
      bfr[n] = *(const bf16x8*)(&Bs[wc * 64 + n * 16 + fr][kg * 8]);
    #pragma unroll
    for (int m = 0; m < 4; ++m)
      #pragma unroll
      for (int n = 0; n < 4; ++n)
        acc[m][n] = __builtin_amdgcn_mfma_f32_16x16x32_bf16(af[m], bfr[n], acc[m][n], 0, 0, 0);
    __syncthreads();
  }
  // epilogue: per m-chunk stage 32x128 f32 in LDS, write 512B-contiguous rows
  #pragma unroll
  for (int m = 0; m < 4; ++m) {
    __syncthreads();
    #pragma unroll
    for (int n = 0; n < 4; ++n)
      #pragma unroll
      for (int r = 0; r < 4; ++r)
        et[wr * 16 + kg * 4 + r][wc * 64 + n * 16 + fr] = acc[m][n][r];
    __syncthreads();
    #pragma unroll
    for (int w = 0; w < 4; ++w) {
      const int idx = w * 256 + t;
      const int lrow = idx >> 5, lc4 = idx & 31;
      const int grow = i0 + (lrow >> 4) * 64 + m * 16 + (lrow & 15);
      const int gcol = j0 + lc4 * 4;
      const float4 bv = *(const float4*)(bias + gcol);
      float4 o;
      o.x = et[lrow][lc4 * 4 + 0] + bv.x;
      o.y = et[lrow][lc4 * 4 + 1] + bv.y;
      o.z = et[lrow][lc4 * 4 + 2] + bv.z;
      o.w = et[lrow][lc4 * 4 + 3] + bv.w;
      *(float4*)(out + (size_t)grow * MD + gcol) = o;
    }
  }
}

extern "C" void kernel_launch(void* const* d_in, const int* in_sizes, int n_in,
                              void* d_out, int out_size, void* d_ws, size_t ws_size,
                              hipStream_t stream) {
  const float* emb = (const float*)d_in[0];
  const int* ei = (const int*)d_in[1];
  const int* esrc = ei;                     // edge_index[0]
  const int* edst = ei + NE;                // edge_index[1]
  const int* send = (const int*)d_in[2];
  const int* recv = (const int*)d_in[3];
  const float* W = (const float*)d_in[4];
  const float* bias = (const float*)d_in[5];
  float* out = (float*)d_out;

  char* ws = (char*)d_ws;
  size_t off = 0;
  auto take = [&](size_t b) {
    char* p = ws + off;
    off = (off + b + 1023) & ~(size_t)1023;
    return p;
  };
  const size_t CSRN = (size_t)NE + 8 * (size_t)NN;  // padded CSR capacity
  int* zblk = (int*)take((size_t)(NBKT + 1 + NN) * 4);  // gcursor|lcnt|mark
  int* gcursor = zblk;                                  // becomes bcnt
  int* lcnt = zblk + NBKT;
  int* mark = zblk + NBKT + 1;
  int* uidx = (int*)take((size_t)NN * 4);   // only read at marked nodes
  float* dinv = (float*)take((size_t)NN * 4);
  int* degI = (int*)take((size_t)NN * 4);
  int* rowstart = (int*)take((size_t)NN * 4);
  int* excl = (int*)take((size_t)NN * 4);
  int* btot = (int*)take(NBKT * 4);
  int* list = (int*)take((size_t)MROWS * 4);
  unsigned* ebuf = (unsigned*)take((size_t)NBKT * SEGCAP * 4);
  int* csr = (int*)take(CSRN * 4);
  unsigned short* x0 = (unsigned short*)take((size_t)(NN + 1) * DD * 2);
  unsigned short* x1 = (unsigned short*)take((size_t)(NN + 1) * DD * 2);
  unsigned short* x2 = (unsigned short*)take((size_t)(NN + 1) * DD * 2);
  unsigned short* zbuf = (unsigned short*)take((size_t)MROWS * MD * 2);
  unsigned short* Wbf = (unsigned short*)take((size_t)MD * MD * 2);
  (void)ws_size; (void)in_sizes; (void)n_in; (void)out_size;

  hipMemsetAsync(zblk, 0, (size_t)(NBKT + 1 + NN) * 4, stream);

  // ---- CSR build + mark/compact fused as tail blocks ----
  k_binA_mark<<<NBINA + NMARK, 256, 0, stream>>>(esrc, edst, gcursor, ebuf,
                                                 send, recv, mark);
  k_degB_compact<<<NBKT + NCOMP, 256, 0, stream>>>(ebuf, gcursor, degI, dinv, excl,
                                                   btot, x0, x1, x2, mark, list,
                                                   lcnt, uidx);
  k_binB<<<NBKT, 256, 0, stream>>>(ebuf, gcursor, btot, excl, rowstart, csr);
  k_conv_emb2<<<NN / 4 + MD * MD / 4 / 256, 256, 0, stream>>>(emb, dinv, x0, W, Wbf);

  // 2 full feature-split layers; fused final layer + z-normalize
  k_aggs<<<4096, 256, 0, stream>>>(rowstart, degI, csr, dinv, x0, x1);
  k_aggs<<<4096, 256, 0, stream>>>(rowstart, degI, csr, dinv, x1, x2);
  k_agg3z<<<2048, 256, 0, stream>>>(rowstart, degI, csr, dinv, x0, x1, x2,
                                    zbuf, list, lcnt);

  k_gemm<<<(MROWS / 128) * (MD / 128), 256, 0, stream>>>(zbuf, send, recv, uidx,
                                                         Wbf, bias, out);
}